// Round 4
// baseline (282.334 us; speedup 1.0000x reference)
//
#include <hip/hip_runtime.h>
#include <hip/hip_bf16.h>

typedef __attribute__((ext_vector_type(2))) float f2v;
typedef __attribute__((ext_vector_type(4))) float f4v;
typedef __attribute__((ext_vector_type(8))) short bf8v;

// ---- problem constants ----
#define NPOS 32768            // 32*32*32
#define CCH  192
#define HID  768

// ---- workspace layout (bytes) ----
#define WS_Y    ((size_t)0)           // 2*512*192*64*2 = 25,165,824  conv out bf16, cell layout
#define WS_B1F  ((size_t)25165824)    // 294,912  w1 bf16 B-frag swizzled
#define WS_B2F  ((size_t)25460736)    // 294,912  w2 bf16 B-frag swizzled
#define WS_WP2  ((size_t)25755648)    // 602,112  shifted weight pairs {w[j],w[j-1]} (192*49*8 f2v)
#define WS_TOTAL ((size_t)26357760)

__device__ inline unsigned short f2bf(float f){
  unsigned int u = __float_as_uint(f);
  u += 0x7FFFu + ((u >> 16) & 1u);      // RNE
  return (unsigned short)(u >> 16);
}
__device__ inline float bf2f(unsigned short s){
  return __uint_as_float(((unsigned int)s) << 16);
}
__device__ inline float gelu_f(float x){
  float u = 0.7978845608028654f * x * fmaf(0.044715f, x*x, 1.0f);
  float e = __expf(2.0f*u);
  float th = __fdividef(e - 1.0f, e + 1.0f);
  return 0.5f*x*(1.0f + th);
}

// v_pk_fma_f32 with op_sel broadcast of one 32-bit half of the x pair.
// src0 = weight SGPR pair {w_lo -> out_lo, w_hi -> out_hi}
// src1 = x VGPR pair, op_sel broadcasts lo (L) or hi (H) half to both lanes
// src2 = accumulator (in place)
#define PKFMA_L(A, X, W) \
  asm("v_pk_fma_f32 %0, %2, %1, %0 op_sel:[0,0,0] op_sel_hi:[1,0,1]" \
      : "+v"(A) : "v"(X), "s"(W))
#define PKFMA_H(A, X, W) \
  asm("v_pk_fma_f32 %0, %2, %1, %0 op_sel:[0,1,0] op_sel_hi:[1,1,1]" \
      : "+v"(A) : "v"(X), "s"(W))

// ---------------------------------------------------------------------------
// Kernel 1: depthwise 7x7x7 conv + bias, packed fp32.
// ASMP=1: tap-pair formulation. Ring col j (rel. to thread base) contributes
// weight w[j-d-1] to output d, so the packed pair {out0,out1} takes
// {w[j-1],w[j-2]} = wp2[j-1] and {out2,out3} takes wp2[j-3], each times an
// op_sel BROADCAST of col j from an ALIGNED 64-bit pair -- zero sliding movs.
// j runs 1..10 (col 10 = lo half of the 6th aligned pair); zero-padded wp2
// row ends make boundary taps exact no-ops.
// ASMP=0: fallback C path (scalar weight splat), used only if ws too small.
// Output: bf16 cell-blocked yc[((b*512+cell)*192+c)*64 + tok].
// ---------------------------------------------------------------------------
template<int ASMP>
__global__ __launch_bounds__(256) void conv_dw_kernel(
    const float* __restrict__ x, const float* __restrict__ dw_w,
    const float* __restrict__ dw_b, const double* __restrict__ wpair2,
    unsigned short* __restrict__ yc)
{
  __shared__ float ring[22*528];       // 46,464 B -> 3 blocks/CU

  int bid = blockIdx.x;                // 3072 = 192c * 16(r)
  int c = bid % 192;
  int r = bid / 192;                   // 0..15
  int xq = r & 1, yq = (r >> 1) & 1, zh = (r >> 2) & 1, b = r >> 3;
  int tx0 = xq*16, ty0 = yq*16, zb = zh*16;

  int tid = threadIdx.x;
  const float* xsrc = x + ((size_t)(b*CCH + c))*NPOS;

  // ---- stage input column (weights go through scalar cache)
  for (int idx = tid; idx < 2904; idx += 256) {   // 22 sl x 22 rows x 6 f4
    int sl = idx / 132;
    int rem = idx - sl*132;
    int rr = rem / 6, ci = rem - rr*6;
    int zi = zb - 3 + sl, gy = ty0 - 3 + rr, gx = tx0 - 4 + 4*ci;
    f4v v = {0.f, 0.f, 0.f, 0.f};
    if ((unsigned)zi < 32u && (unsigned)gy < 32u && (unsigned)gx <= 28u)
      v = *(const f4v*)(xsrc + (size_t)zi*1024 + gy*32 + gx);
    *(f4v*)(ring + sl*528 + rr*24 + ci*4) = v;
  }
  __syncthreads();

  int p = tid & 15, zl = tid >> 4;     // 16 patches, 16 z-planes
  int px = p & 3, py = p >> 2;
  int y0 = py*4, px4 = px*4;
  const float* base = ring + zl*528 + y0*24 + px4;

  if constexpr (ASMP) {
    const double* wb2 = wpair2 + (size_t)c*392;   // 49 rows x 8 pairs

    double acc[8];                     // acc[dy*2+h] = outputs dx={2h,2h+1}
    #pragma unroll
    for (int i = 0; i < 8; ++i) acc[i] = 0.0;

    #pragma unroll 1                   // keep body in I-cache
    for (int s = 0; s < 7; ++s) {
      const float* sb = base + s*528;
      const double* wrow = wb2 + s*56;            // [ky*8 + t]
      #pragma unroll
      for (int rr = 0; rr < 10; ++rr) {
        const float* rb = sb + rr*24;
        union { f4v v; double d[2]; } q0, q1, q2;
        q0.v = *(const f4v*)(rb);
        q1.v = *(const f4v*)(rb + 4);
        q2.v = *(const f4v*)(rb + 8);
        double P[6] = {q0.d[0], q0.d[1], q1.d[0], q1.d[1], q2.d[0], q2.d[1]};
        // col j: acc{0,1} += wp2[j-1]*col[j] (j<=8);
        //        acc{2,3} += wp2[j-3]*col[j] (j>=3)
        #pragma unroll
        for (int j = 1; j <= 10; ++j) {
          #pragma unroll
          for (int dy = 0; dy < 4; ++dy) {
            int ky = rr - dy;
            if (ky < 0 || ky > 6) continue;        // compile-time pruned
            if (j <= 8) {
              double w = wrow[ky*8 + (j-1)];
              if (j & 1) { PKFMA_H(acc[dy*2+0], P[j>>1], w); }
              else       { PKFMA_L(acc[dy*2+0], P[j>>1], w); }
            }
            if (j >= 3) {
              double w = wrow[ky*8 + (j-3)];
              if (j & 1) { PKFMA_H(acc[dy*2+1], P[j>>1], w); }
              else       { PKFMA_L(acc[dy*2+1], P[j>>1], w); }
            }
          }
        }
      }
    }

    // ---- store bf16 to cell-blocked layout
    float bias = dw_b[c];
    int z = zb + zl;
    int cz = z >> 2, cx = (tx0 >> 2) + px, cy = (ty0 >> 2) + py;
    int cell = cz*64 + cy*8 + cx;
    unsigned short* ybase = yc + (((size_t)(b*512 + cell))*192 + c)*64;
    int tokz = (z & 3)*16;
    #pragma unroll
    for (int dy = 0; dy < 4; ++dy) {
      union { double d; float f[2]; } u0, u1;
      u0.d = acc[dy*2+0]; u1.d = acc[dy*2+1];
      ushort4 o;
      o.x = f2bf(u0.f[0] + bias);
      o.y = f2bf(u0.f[1] + bias);
      o.z = f2bf(u1.f[0] + bias);
      o.w = f2bf(u1.f[1] + bias);
      *(ushort4*)(ybase + tokz + dy*4) = o;
    }
  } else {
    // ---- fallback: original C path, scalar weight splat
    const float* wbase = dw_w + (size_t)c*343;
    f2v acc[8];
    #pragma unroll
    for (int i = 0; i < 8; ++i) acc[i] = (f2v){0.f, 0.f};

    #pragma unroll 1
    for (int s = 0; s < 7; ++s) {
      const float* sb = base + s*528;
      f4v n0 = *(const f4v*)(sb);
      f4v n1 = *(const f4v*)(sb + 4);
      f4v n2 = *(const f4v*)(sb + 8);
      #pragma unroll
      for (int rr = 0; rr < 10; ++rr) {
        f4v r0 = n0, r1 = n1, r2 = n2;
        if (rr < 9) {
          n0 = *(const f4v*)(sb + (rr+1)*24);
          n1 = *(const f4v*)(sb + (rr+1)*24 + 4);
          n2 = *(const f4v*)(sb + (rr+1)*24 + 8);
        }
        f2v pr[10];
        pr[1] = (f2v){r0[1], r0[2]};
        pr[2] = (f2v){r0[2], r0[3]};
        pr[3] = (f2v){r0[3], r1[0]};
        pr[4] = (f2v){r1[0], r1[1]};
        pr[5] = (f2v){r1[1], r1[2]};
        pr[6] = (f2v){r1[2], r1[3]};
        pr[7] = (f2v){r1[3], r2[0]};
        pr[8] = (f2v){r2[0], r2[1]};
        pr[9] = (f2v){r2[1], r2[2]};
        #pragma unroll
        for (int dy = 0; dy < 4; ++dy) {
          int ky = rr - dy;
          if (ky < 0 || ky > 6) continue;
          #pragma unroll
          for (int kx = 0; kx < 7; ++kx) {
            float w = wbase[s*49 + ky*7 + kx];
            f2v wv = (f2v){w, w};
            acc[dy*2+0] = __builtin_elementwise_fma(wv, pr[kx+1], acc[dy*2+0]);
            acc[dy*2+1] = __builtin_elementwise_fma(wv, pr[kx+3], acc[dy*2+1]);
          }
        }
      }
    }

    float bias = dw_b[c];
    int z = zb + zl;
    int cz = z >> 2, cx = (tx0 >> 2) + px, cy = (ty0 >> 2) + py;
    int cell = cz*64 + cy*8 + cx;
    unsigned short* ybase = yc + (((size_t)(b*512 + cell))*192 + c)*64;
    int tokz = (z & 3)*16;
    #pragma unroll
    for (int dy = 0; dy < 4; ++dy) {
      ushort4 o;
      o.x = f2bf(acc[dy*2+0][0] + bias);
      o.y = f2bf(acc[dy*2+0][1] + bias);
      o.z = f2bf(acc[dy*2+1][0] + bias);
      o.w = f2bf(acc[dy*2+1][1] + bias);
      *(ushort4*)(ybase + tokz + dy*4) = o;
    }
  }
}

// ---------------------------------------------------------------------------
// Kernel 2: weight prep. w1/w2 -> bf16 MFMA-B-fragment order; dw_w ->
// shifted tap pairs wp2[c][s][ky][t] = {w[t] (t<7), w[t-1] (t>0)}, t=0..7,
// for the conv's op_sel tap-pair path.
// B-frag (16x16x32): element (k,n) -> lane=((k%32)/8)*16+(n%16), byte j=k%8.
// ---------------------------------------------------------------------------
__global__ __launch_bounds__(256) void prep_w_kernel(
    const float* __restrict__ w1, const float* __restrict__ w2,
    const float* __restrict__ dw_w,
    unsigned short* __restrict__ b1f, unsigned short* __restrict__ b2f,
    f2v* __restrict__ wp2)
{
  int gid = blockIdx.x*256 + threadIdx.x;
  if (gid < 18432) {
    int fi = gid;                         // w1 (C=192 x HID=768)
    int lane = fi & 63, fr = fi >> 6;
    int nt = fr / 6, ks = fr - nt*6;
    int n  = nt*16 + (lane & 15);
    int kb = ks*32 + (lane >> 4)*8;
    #pragma unroll
    for (int j = 0; j < 8; ++j) b1f[fi*8 + j] = f2bf(w1[(kb+j)*HID + n]);
  } else if (gid < 36864) {
    int fi = gid - 18432;                 // w2 (HID=768 x C=192)
    int lane = fi & 63, fr = fi >> 6;
    int nt = fr / 24, ks = fr - nt*24;
    int n  = nt*16 + (lane & 15);
    int kb = ks*32 + (lane >> 4)*8;
    #pragma unroll
    for (int j = 0; j < 8; ++j) b2f[fi*8 + j] = f2bf(w2[(kb+j)*CCH + n]);
  } else if (gid < 46272) {
    int ci = gid - 36864;                 // 192*49 (c, s, ky) rows
    int cch = ci / 49, t = ci - cch*49;   // t = s*7 + ky
    const float* wr = dw_w + cch*343 + t*7;
    #pragma unroll
    for (int j = 0; j < 8; ++j) {
      float lo = (j <= 6) ? wr[j] : 0.f;
      float hi = (j >= 1) ? wr[j-1] : 0.f;
      wp2[ci*8 + j] = (f2v){lo, hi};
    }
  }
}

// ---------------------------------------------------------------------------
// Kernel 3: fused LN + MLP per active cell, software-pipelined B loads:
// B2r(ch) loaded at loop top (drain covered by GEMM1); B1r(ch+1) prefetched
// right after GEMM1's last use (drain covered by gelu+barrier+GEMM2).
// A-fragments in LDS; ln_w/ln_b as batched f4v loads.
// ---------------------------------------------------------------------------
__global__ __launch_bounds__(256) void mlp_kernel(
    const unsigned short* __restrict__ yc, const unsigned short* __restrict__ b1f,
    const unsigned short* __restrict__ b2f, const float* __restrict__ b1,
    const float* __restrict__ b2, const float* __restrict__ gamma,
    const float* __restrict__ ln_w, const float* __restrict__ ln_b,
    const int* __restrict__ mask, float* __restrict__ out)
{
  int bid = blockIdx.x;
  int b = bid >> 9, cell = bid & 511;
  int cz = cell >> 6, cy = (cell >> 3) & 7, cx = cell & 7;
  int z0 = cz*4, y0 = cy*4, x0 = cx*4;
  int tid = threadIdx.x, wave = tid >> 6, lane = tid & 63;
  int lq = lane >> 4, ln15 = lane & 15;

  if (mask[bid] == 0) {
    f4v z4 = {0.f, 0.f, 0.f, 0.f};
    #pragma unroll
    for (int pp = 0; pp < 12; ++pp) {
      int i4 = tid + 256*pp;              // 0..3071
      int c = i4 >> 4, rem = i4 & 15;
      int dz = rem >> 2, dy = rem & 3;
      *(f4v*)(out + ((size_t)(b*CCH + c))*NPOS
                  + (size_t)(z0+dz)*1024 + (y0+dy)*32 + x0) = z4;
    }
    return;
  }

  // ---- LDS: ymat (phase 1) unioned with hbuf (phase 2); aFrag persistent
  __shared__ __align__(16) char uni[26112];       // max(192*68*2, 8192*2)
  unsigned short* ymat = (unsigned short*)uni;    // stride 68
  unsigned short* hbuf = (unsigned short*)uni;    // 8192 ushorts, A2-frag order
  __shared__ unsigned short aFrag[12288];         // 24 KB, A1-frag order
  __shared__ float sred[2][4][64];
  __shared__ float murs[2][64];
  // total 53,248 B -> 3 blocks/CU

  const unsigned short* ysrc = yc + (size_t)bid*12288;

  // ---- stage yc -> ymat (coalesced ushort4)
  #pragma unroll
  for (int k = 0; k < 12; ++k) {
    int idx = tid + 256*k;                  // 0..3071
    int c = idx >> 4, t4 = idx & 15;
    *(ushort4*)(ymat + c*68 + t4*4) = *(const ushort4*)(ysrc + c*64 + t4*4);
  }
  __syncthreads();

  // ---- LN stats: thread (tok = tid&63, part = tid>>6) sums 48 channels
  {
    int tok = tid & 63, part = tid >> 6;
    float S = 0.f, Q = 0.f;
    #pragma unroll
    for (int j = 0; j < 48; ++j) {
      float v = bf2f(ymat[(part*48 + j)*68 + tok]);
      S += v; Q = fmaf(v, v, Q);
    }
    sred[0][part][tok] = S; sred[1][part][tok] = Q;
  }
  __syncthreads();
  if (tid < 64) {
    float S = sred[0][0][tid] + sred[0][1][tid] + sred[0][2][tid] + sred[0][3][tid];
    float Q = sred[1][0][tid] + sred[1][1][tid] + sred[1][2][tid] + sred[1][3][tid];
    float m = S*(1.f/192.f);
    float var = Q*(1.f/192.f) - m*m;
    murs[0][tid] = m;
    murs[1][tid] = rsqrtf(var + 1e-6f);
  }
  __syncthreads();

  // ---- build A-fragments into aFrag (6 frags/thread, b128 coalesced writes)
  #pragma unroll
  for (int k = 0; k < 6; ++k) {
    int fi = tid + 256*k;                   // 0..1535
    int lane2 = fi & 63, rest = fi >> 6;
    int mt = rest / 6, ks = rest - mt*6;
    int tok = mt*16 + (lane2 & 15);
    int cc0 = ks*32 + (lane2 >> 4)*8;
    float m = murs[0][tok], rs = murs[1][tok];
    f4v lw0 = *(const f4v*)(ln_w + cc0), lw1 = *(const f4v*)(ln_w + cc0 + 4);
    f4v lb0 = *(const f4v*)(ln_b + cc0), lb1 = *(const f4v*)(ln_b + cc0 + 4);
    union { bf8v v; unsigned short u[8]; } pk;
    #pragma unroll
    for (int j = 0; j < 4; ++j) {
      float v0 = (bf2f(ymat[(cc0+j)*68 + tok])   - m)*rs*lw0[j] + lb0[j];
      float v1 = (bf2f(ymat[(cc0+4+j)*68 + tok]) - m)*rs*lw1[j] + lb1[j];
      pk.u[j] = f2bf(v0); pk.u[4+j] = f2bf(v1);
    }
    *(bf8v*)(aFrag + fi*8) = pk.v;
  }
  __syncthreads();                          // aFrag ready; ymat dead

  f4v acc2[4][3];
  #pragma unroll
  for (int mt = 0; mt < 4; ++mt)
    #pragma unroll
    for (int nt = 0; nt < 3; ++nt)
      acc2[mt][nt] = (f4v){0.f, 0.f, 0.f, 0.f};

  // ---- pipelined B fragment pointers (ushort units)
  const unsigned short* p1base = b1f + wave*2*3072 + lane*8;   // + ch*24576
  const unsigned short* p2base = b2f + wave*3*12288 + lane*8;  // + ch*2048

  bf8v B1r[12];
  #pragma unroll
  for (int i = 0; i < 12; ++i) {            // preload B1 for ch=0
    int jj = i / 6, ks = i - jj*6;
    B1r[i] = *(const bf8v*)(p1base + jj*3072 + ks*512);
  }

  #pragma unroll 1                          // keep body in I-cache
  for (int ch = 0; ch < 6; ++ch) {
    // ---- B2r(ch): 12 outstanding loads, drain covered by GEMM1
    bf8v B2r[12];
    const unsigned short* p2 = p2base + ch*2048;
    #pragma unroll
    for (int ks2 = 0; ks2 < 4; ++ks2)
      #pragma unroll
      for (int nt = 0; nt < 3; ++nt)
        B2r[ks2*3 + nt] = *(const bf8v*)(p2 + nt*12288 + ks2*512);

    // ---- GEMM1: A from LDS, B1 from regs
    f4v a1[2][4];
    #pragma unroll
    for (int jj = 0; jj < 2; ++jj)
      #pragma unroll
      for (int mt = 0; mt < 4; ++mt) a1[jj][mt] = (f4v){0.f,0.f,0.f,0.f};
    #pragma unroll
    for (int ks = 0; ks < 6; ++ks) {
      bf8v Af[4];
      #pragma unroll
      for (int mt = 0; mt < 4; ++mt)
        Af[mt] = *(const bf8v*)(aFrag + ((mt*6 + ks)*64 + lane)*8);
      #pragma unroll
      for (int jj = 0; jj < 2; ++jj)
        #pragma unroll
        for (int mt = 0; mt < 4; ++mt)
          a1[jj][mt] = __builtin_amdgcn_mfma_f32_16x16x32_bf16(Af[mt], B1r[jj*6+ks], a1[jj][mt], 0, 0, 0);
    }

    // ---- prefetch B1r(ch+1): drain covered by gelu + barrier + GEMM2
    if (ch < 5) {
      const unsigned short* p1 = p1base + (ch+1)*24576;
      #pragma unroll
      for (int i = 0; i < 12; ++i) {
        int jj = i / 6, ks = i - jj*6;
        B1r[i] = *(const bf8v*)(p1 + jj*3072 + ks*512);
      }
    }

    // ---- bias + gelu -> hbuf (A2-frag order)
    #pragma unroll
    for (int jj = 0; jj < 2; ++jj) {
      float b1v = b1[(ch*8 + wave*2 + jj)*16 + ln15];
      int lane_hi = jj*2 + (ln15 >> 3);
      #pragma unroll
      for (int mt = 0; mt < 4; ++mt)
        #pragma unroll
        for (int rr = 0; rr < 4; ++rr) {
          float g = gelu_f(a1[jj][mt][rr] + b1v);
          int elem = ((mt*4 + wave)*64 + lane_hi*16 + (lq*4 + rr))*8 + (lane & 7);
          hbuf[elem] = f2bf(g);
        }
    }
    __syncthreads();
    // ---- GEMM2 partial: acc2 += h_chunk @ w2[ch*128.., :]
    #pragma unroll
    for (int ks2 = 0; ks2 < 4; ++ks2) {
      bf8v A2[4];
      #pragma unroll
      for (int mt = 0; mt < 4; ++mt)
        A2[mt] = *(const bf8v*)(hbuf + ((mt*4 + ks2)*64 + lane)*8);
      #pragma unroll
      for (int nt = 0; nt < 3; ++nt)
        #pragma unroll
        for (int mt = 0; mt < 4; ++mt)
          acc2[mt][nt] = __builtin_amdgcn_mfma_f32_16x16x32_bf16(A2[mt], B2r[ks2*3+nt], acc2[mt][nt], 0, 0, 0);
    }
    __syncthreads();                        // hbuf reused next ch
  }

  // ---- epilogue: gamma*(acc+b2), f4v store channels-first
  #pragma unroll
  for (int nt = 0; nt < 3; ++nt) {
    int c = (wave*3 + nt)*16 + ln15;
    float gm = gamma[c], bb = b2[c];
    size_t cbase = ((size_t)(b*CCH + c))*NPOS + (size_t)(y0 + lq)*32 + x0;
    #pragma unroll
    for (int mt = 0; mt < 4; ++mt) {
      f4v o;
      o[0] = gm*(acc2[mt][nt][0] + bb);
      o[1] = gm*(acc2[mt][nt][1] + bb);
      o[2] = gm*(acc2[mt][nt][2] + bb);
      o[3] = gm*(acc2[mt][nt][3] + bb);
      *(f4v*)(out + cbase + (size_t)(z0 + mt)*1024) = o;
    }
  }
}

// ---------------------------------------------------------------------------
extern "C" void kernel_launch(void* const* d_in, const int* in_sizes, int n_in,
                              void* d_out, int out_size, void* d_ws, size_t ws_size,
                              hipStream_t stream) {
  const float* x     = (const float*)d_in[0];
  const int*   mask  = (const int*)  d_in[1];
  const float* dw_w  = (const float*)d_in[2];
  const float* dw_b  = (const float*)d_in[3];
  const float* ln_w  = (const float*)d_in[4];
  const float* ln_b  = (const float*)d_in[5];
  const float* w1    = (const float*)d_in[6];
  const float* b1    = (const float*)d_in[7];
  const float* w2    = (const float*)d_in[8];
  const float* b2    = (const float*)d_in[9];
  const float* gamma = (const float*)d_in[10];
  float* out = (float*)d_out;
  char* ws = (char*)d_ws;

  unsigned short* yc  = (unsigned short*)(ws + WS_Y);
  unsigned short* b1f = (unsigned short*)(ws + WS_B1F);
  unsigned short* b2f = (unsigned short*)(ws + WS_B2F);
  double*         wp2 = (double*)(ws + WS_WP2);

  bool wp_ok = ws_size >= WS_TOTAL;
  int prep_grid = wp_ok ? 181 : 144;        // 181 covers the wp2 branch
  prep_w_kernel<<<prep_grid, 256, 0, stream>>>(w1, w2, dw_w, b1f, b2f, (f2v*)wp2);
  if (wp_ok)
    conv_dw_kernel<1><<<3072, 256, 0, stream>>>(x, dw_w, dw_b, wp2, yc);
  else
    conv_dw_kernel<0><<<3072, 256, 0, stream>>>(x, dw_w, dw_b, wp2, yc);
  mlp_kernel<<<1024, 256, 0, stream>>>(yc, b1f, b2f, b1, b2, gamma, ln_w, ln_b, mask, out);
}

// Round 5
// 270.299 us; speedup vs baseline: 1.0445x; 1.0445x over previous
//
#include <hip/hip_runtime.h>
#include <hip/hip_bf16.h>

typedef __attribute__((ext_vector_type(2))) float f2v;
typedef __attribute__((ext_vector_type(4))) float f4v;
typedef __attribute__((ext_vector_type(8))) short bf8v;

// ---- problem constants ----
#define NPOS 32768            // 32*32*32
#define CCH  192
#define HID  768

// ---- workspace layout (bytes) ----
#define WS_Y    ((size_t)0)           // 2*512*192*64*2 = 25,165,824  conv out bf16, cell layout
#define WS_B1F  ((size_t)25165824)    // 294,912  w1 bf16 B-frag swizzled
#define WS_B2F  ((size_t)25460736)    // 294,912  w2 bf16 B-frag swizzled
#define WS_WPF  ((size_t)25755648)    // 301,056  f16 dot2 weight-pair words (192*49*8 u32)
#define WS_TOTAL ((size_t)26357760)   // (slot sized 602,112 from prior layout; wpf uses half)

__device__ inline unsigned short f2bf(float f){
  unsigned int u = __float_as_uint(f);
  u += 0x7FFFu + ((u >> 16) & 1u);      // RNE
  return (unsigned short)(u >> 16);
}
__device__ inline float bf2f(unsigned short s){
  return __uint_as_float(((unsigned int)s) << 16);
}
__device__ inline float gelu_f(float x){
  float u = 0.7978845608028654f * x * fmaf(0.044715f, x*x, 1.0f);
  float e = __expf(2.0f*u);
  float th = __fdividef(e - 1.0f, e + 1.0f);
  return 0.5f*x*(1.0f + th);
}

// v_dot2_f32_f16: A += X.lo*W.lo + X.hi*W.hi  (f16 pairs, f32 accumulate)
// X = packed input pair from LDS (VGPR dword), W = packed weight pair (SGPR,
// uniform per block -> scalar pipe; 1 SGPR operand per VALU instr is legal).
#define DOT2(A, X, W) \
  asm("v_dot2_f32_f16 %0, %1, %2, %0" : "+v"(A) : "v"(X), "s"(W))

// ---------------------------------------------------------------------------
// Kernel 1 (main): depthwise 7x7x7 conv + bias via v_dot2_f32_f16.
// Ring staged in f16 (23.2 KB -> 6 blocks/CU, double the occupancy of the
// fp32 ring) as aligned col-pairs [2i,2i+1]. Geometry (verified in r4): ring
// col j rel. to thread base px4 feeds output dx with weight w[j-dx-1].
// Per (ky,kz) row each output dx consumes 4 aligned dwords with shifted
// f16 weight pairs:
//   dx=0: D[t]   * W0[t]={w[2t-1]|0, w[2t]}      t=0..3
//   dx=1: D[t+1] * W1[t]={w[2t],    w[2t+1]|0}
//   dx=2: D[t+1] * W0[t]
//   dx=3: D[t+2] * W1[t]
// (D[k] = ring cols [2k,2k+1] rel. to base; cols 0..11 = 3x ds_read_b64.)
// Output: bf16 cell-blocked yc[((b*512+cell)*192+c)*64 + tok].
// ---------------------------------------------------------------------------
__global__ __launch_bounds__(256, 6) void conv_dw_f16_kernel(
    const float* __restrict__ x, const float* __restrict__ dw_b,
    const unsigned int* __restrict__ wpf, unsigned short* __restrict__ yc)
{
  __shared__ unsigned short ring[22*528];   // f16, 23,232 B -> 6 blocks/CU

  int bid = blockIdx.x;                // 3072 = 192c * 16(r)
  int c = bid % 192;
  int r = bid / 192;                   // 0..15
  int xq = r & 1, yq = (r >> 1) & 1, zh = (r >> 2) & 1, b = r >> 3;
  int tx0 = xq*16, ty0 = yq*16, zb = zh*16;

  int tid = threadIdx.x;
  const float* xsrc = x + ((size_t)(b*CCH + c))*NPOS;

  // ---- stage input column, f32 -> f16 (RNE via compiler casts)
  for (int idx = tid; idx < 2904; idx += 256) {   // 22 sl x 22 rows x 6 quads
    int sl = idx / 132;
    int rem = idx - sl*132;
    int rr = rem / 6, ci = rem - rr*6;
    int zi = zb - 3 + sl, gy = ty0 - 3 + rr, gx = tx0 - 4 + 4*ci;
    f4v v = {0.f, 0.f, 0.f, 0.f};
    if ((unsigned)zi < 32u && (unsigned)gy < 32u && (unsigned)gx <= 28u)
      v = *(const f4v*)(xsrc + (size_t)zi*1024 + gy*32 + gx);
    union { _Float16 h[4]; uint2 u2; } pk;
    pk.h[0] = (_Float16)v[0]; pk.h[1] = (_Float16)v[1];
    pk.h[2] = (_Float16)v[2]; pk.h[3] = (_Float16)v[3];
    *(uint2*)(ring + sl*528 + rr*24 + ci*4) = pk.u2;   // 8B-aligned
  }
  __syncthreads();

  int p = tid & 15, zl = tid >> 4;     // 16 patches, 16 z-planes
  int px = p & 3, py = p >> 2;
  int y0 = py*4, px4 = px*4;
  const unsigned short* base = ring + zl*528 + y0*24 + px4;

  const unsigned int* wb = wpf + (size_t)c*392;   // 49 rows x 8 words

  float acc[4][4];                     // [dy][dx]
  #pragma unroll
  for (int i = 0; i < 4; ++i)
    #pragma unroll
    for (int j = 0; j < 4; ++j) acc[i][j] = 0.f;

  #pragma unroll 1                     // keep body in I-cache
  for (int s = 0; s < 7; ++s) {        // s = kz
    const unsigned short* sb = base + s*528;
    const unsigned int* wrow = wb + s*56;          // [ky*8 + p*4 + t]
    #pragma unroll
    for (int rr = 0; rr < 10; ++rr) {
      const unsigned short* rb = sb + rr*24;
      uint2 q0 = *(const uint2*)(rb);
      uint2 q1 = *(const uint2*)(rb + 4);
      uint2 q2 = *(const uint2*)(rb + 8);
      unsigned int D[6] = {q0.x, q0.y, q1.x, q1.y, q2.x, q2.y};
      #pragma unroll
      for (int dy = 0; dy < 4; ++dy) {
        int ky = rr - dy;
        if (ky < 0 || ky > 6) continue;            // compile-time pruned
        const unsigned int* wk = wrow + ky*8;
        #pragma unroll
        for (int t = 0; t < 4; ++t) {
          DOT2(acc[dy][0], D[t],   wk[t]);
          DOT2(acc[dy][1], D[t+1], wk[4+t]);
          DOT2(acc[dy][2], D[t+1], wk[t]);
          DOT2(acc[dy][3], D[t+2], wk[4+t]);
        }
      }
    }
  }

  // ---- store bf16 to cell-blocked layout
  float bias = dw_b[c];
  int z = zb + zl;
  int cz = z >> 2, cx = (tx0 >> 2) + px, cy = (ty0 >> 2) + py;
  int cell = cz*64 + cy*8 + cx;
  unsigned short* ybase = yc + (((size_t)(b*512 + cell))*192 + c)*64;
  int tokz = (z & 3)*16;
  #pragma unroll
  for (int dy = 0; dy < 4; ++dy) {
    ushort4 o;
    o.x = f2bf(acc[dy][0] + bias);
    o.y = f2bf(acc[dy][1] + bias);
    o.z = f2bf(acc[dy][2] + bias);
    o.w = f2bf(acc[dy][3] + bias);
    *(ushort4*)(ybase + tokz + dy*4) = o;
  }
}

// ---------------------------------------------------------------------------
// Kernel 1 (fallback, ws too small): fp32 C path, scalar weight splat.
// ---------------------------------------------------------------------------
__global__ __launch_bounds__(256) void conv_dw_f32_kernel(
    const float* __restrict__ x, const float* __restrict__ dw_w,
    const float* __restrict__ dw_b, unsigned short* __restrict__ yc)
{
  __shared__ float ring[22*528];

  int bid = blockIdx.x;
  int c = bid % 192;
  int r = bid / 192;
  int xq = r & 1, yq = (r >> 1) & 1, zh = (r >> 2) & 1, b = r >> 3;
  int tx0 = xq*16, ty0 = yq*16, zb = zh*16;

  int tid = threadIdx.x;
  const float* xsrc = x + ((size_t)(b*CCH + c))*NPOS;

  for (int idx = tid; idx < 2904; idx += 256) {
    int sl = idx / 132;
    int rem = idx - sl*132;
    int rr = rem / 6, ci = rem - rr*6;
    int zi = zb - 3 + sl, gy = ty0 - 3 + rr, gx = tx0 - 4 + 4*ci;
    f4v v = {0.f, 0.f, 0.f, 0.f};
    if ((unsigned)zi < 32u && (unsigned)gy < 32u && (unsigned)gx <= 28u)
      v = *(const f4v*)(xsrc + (size_t)zi*1024 + gy*32 + gx);
    *(f4v*)(ring + sl*528 + rr*24 + ci*4) = v;
  }
  __syncthreads();

  int p = tid & 15, zl = tid >> 4;
  int px = p & 3, py = p >> 2;
  int y0 = py*4, px4 = px*4;
  const float* base = ring + zl*528 + y0*24 + px4;
  const float* wbase = dw_w + (size_t)c*343;

  f2v acc[8];
  #pragma unroll
  for (int i = 0; i < 8; ++i) acc[i] = (f2v){0.f, 0.f};

  #pragma unroll 1
  for (int s = 0; s < 7; ++s) {
    const float* sb = base + s*528;
    f4v n0 = *(const f4v*)(sb);
    f4v n1 = *(const f4v*)(sb + 4);
    f4v n2 = *(const f4v*)(sb + 8);
    #pragma unroll
    for (int rr = 0; rr < 10; ++rr) {
      f4v r0 = n0, r1 = n1, r2 = n2;
      if (rr < 9) {
        n0 = *(const f4v*)(sb + (rr+1)*24);
        n1 = *(const f4v*)(sb + (rr+1)*24 + 4);
        n2 = *(const f4v*)(sb + (rr+1)*24 + 8);
      }
      f2v pr[10];
      pr[1] = (f2v){r0[1], r0[2]};
      pr[2] = (f2v){r0[2], r0[3]};
      pr[3] = (f2v){r0[3], r1[0]};
      pr[4] = (f2v){r1[0], r1[1]};
      pr[5] = (f2v){r1[1], r1[2]};
      pr[6] = (f2v){r1[2], r1[3]};
      pr[7] = (f2v){r1[3], r2[0]};
      pr[8] = (f2v){r2[0], r2[1]};
      pr[9] = (f2v){r2[1], r2[2]};
      #pragma unroll
      for (int dy = 0; dy < 4; ++dy) {
        int ky = rr - dy;
        if (ky < 0 || ky > 6) continue;
        #pragma unroll
        for (int kx = 0; kx < 7; ++kx) {
          float w = wbase[s*49 + ky*7 + kx];
          f2v wv = (f2v){w, w};
          acc[dy*2+0] = __builtin_elementwise_fma(wv, pr[kx+1], acc[dy*2+0]);
          acc[dy*2+1] = __builtin_elementwise_fma(wv, pr[kx+3], acc[dy*2+1]);
        }
      }
    }
  }

  float bias = dw_b[c];
  int z = zb + zl;
  int cz = z >> 2, cx = (tx0 >> 2) + px, cy = (ty0 >> 2) + py;
  int cell = cz*64 + cy*8 + cx;
  unsigned short* ybase = yc + (((size_t)(b*512 + cell))*192 + c)*64;
  int tokz = (z & 3)*16;
  #pragma unroll
  for (int dy = 0; dy < 4; ++dy) {
    ushort4 o;
    o.x = f2bf(acc[dy*2+0][0] + bias);
    o.y = f2bf(acc[dy*2+0][1] + bias);
    o.z = f2bf(acc[dy*2+1][0] + bias);
    o.w = f2bf(acc[dy*2+1][1] + bias);
    *(ushort4*)(ybase + tokz + dy*4) = o;
  }
}

// ---------------------------------------------------------------------------
// Kernel 2: weight prep. w1/w2 -> bf16 MFMA-B-fragment order; dw_w ->
// f16 dot2 weight-pair words wpf[(c*49 + s*7 + ky)*8 + p*4 + t]:
//   p=0 (even dx): {w[2t-1]|0, w[2t]}   p=1 (odd dx): {w[2t], w[2t+1]|0}
// B-frag (16x16x32): element (k,n) -> lane=((k%32)/8)*16+(n%16), byte j=k%8.
// ---------------------------------------------------------------------------
__global__ __launch_bounds__(256) void prep_w_kernel(
    const float* __restrict__ w1, const float* __restrict__ w2,
    const float* __restrict__ dw_w,
    unsigned short* __restrict__ b1f, unsigned short* __restrict__ b2f,
    unsigned int* __restrict__ wpf)
{
  int gid = blockIdx.x*256 + threadIdx.x;
  if (gid < 18432) {
    int fi = gid;                         // w1 (C=192 x HID=768)
    int lane = fi & 63, fr = fi >> 6;
    int nt = fr / 6, ks = fr - nt*6;
    int n  = nt*16 + (lane & 15);
    int kb = ks*32 + (lane >> 4)*8;
    #pragma unroll
    for (int j = 0; j < 8; ++j) b1f[fi*8 + j] = f2bf(w1[(kb+j)*HID + n]);
  } else if (gid < 36864) {
    int fi = gid - 18432;                 // w2 (HID=768 x C=192)
    int lane = fi & 63, fr = fi >> 6;
    int nt = fr / 24, ks = fr - nt*24;
    int n  = nt*16 + (lane & 15);
    int kb = ks*32 + (lane >> 4)*8;
    #pragma unroll
    for (int j = 0; j < 8; ++j) b2f[fi*8 + j] = f2bf(w2[(kb+j)*CCH + n]);
  } else if (gid < 46272) {
    int ci = gid - 36864;                 // 192*49 (c, s*7+ky) rows
    int cch = ci / 49, t7 = ci - cch*49;
    const float* wr = dw_w + cch*343 + t7*7;
    float w[8];
    #pragma unroll
    for (int j = 0; j < 7; ++j) w[j] = wr[j];
    w[7] = 0.f;
    union { _Float16 h[2]; unsigned int u; } pk;
    #pragma unroll
    for (int t = 0; t < 4; ++t) {         // p=0: {w[2t-1]|0, w[2t]}
      pk.h[0] = (t == 0) ? (_Float16)0.f : (_Float16)w[2*t-1];
      pk.h[1] = (_Float16)w[2*t];
      wpf[ci*8 + t] = pk.u;
    }
    #pragma unroll
    for (int t = 0; t < 4; ++t) {         // p=1: {w[2t], w[2t+1]|0}
      pk.h[0] = (_Float16)w[2*t];
      pk.h[1] = (_Float16)w[2*t+1];
      wpf[ci*8 + 4 + t] = pk.u;
    }
  }
}

// ---------------------------------------------------------------------------
// Kernel 3: fused LN + MLP per active cell, software-pipelined B loads:
// B2r(ch) loaded at loop top (drain covered by GEMM1); B1r(ch+1) prefetched
// right after GEMM1's last use (drain covered by gelu+barrier+GEMM2).
// A-fragments in LDS; ln_w/ln_b as batched f4v loads.
// ---------------------------------------------------------------------------
__global__ __launch_bounds__(256) void mlp_kernel(
    const unsigned short* __restrict__ yc, const unsigned short* __restrict__ b1f,
    const unsigned short* __restrict__ b2f, const float* __restrict__ b1,
    const float* __restrict__ b2, const float* __restrict__ gamma,
    const float* __restrict__ ln_w, const float* __restrict__ ln_b,
    const int* __restrict__ mask, float* __restrict__ out)
{
  int bid = blockIdx.x;
  int b = bid >> 9, cell = bid & 511;
  int cz = cell >> 6, cy = (cell >> 3) & 7, cx = cell & 7;
  int z0 = cz*4, y0 = cy*4, x0 = cx*4;
  int tid = threadIdx.x, wave = tid >> 6, lane = tid & 63;
  int lq = lane >> 4, ln15 = lane & 15;

  if (mask[bid] == 0) {
    f4v z4 = {0.f, 0.f, 0.f, 0.f};
    #pragma unroll
    for (int pp = 0; pp < 12; ++pp) {
      int i4 = tid + 256*pp;              // 0..3071
      int c = i4 >> 4, rem = i4 & 15;
      int dz = rem >> 2, dy = rem & 3;
      *(f4v*)(out + ((size_t)(b*CCH + c))*NPOS
                  + (size_t)(z0+dz)*1024 + (y0+dy)*32 + x0) = z4;
    }
    return;
  }

  // ---- LDS: ymat (phase 1) unioned with hbuf (phase 2); aFrag persistent
  __shared__ __align__(16) char uni[26112];       // max(192*68*2, 8192*2)
  unsigned short* ymat = (unsigned short*)uni;    // stride 68
  unsigned short* hbuf = (unsigned short*)uni;    // 8192 ushorts, A2-frag order
  __shared__ unsigned short aFrag[12288];         // 24 KB, A1-frag order
  __shared__ float sred[2][4][64];
  __shared__ float murs[2][64];
  // total 53,248 B -> 3 blocks/CU

  const unsigned short* ysrc = yc + (size_t)bid*12288;

  // ---- stage yc -> ymat (coalesced ushort4)
  #pragma unroll
  for (int k = 0; k < 12; ++k) {
    int idx = tid + 256*k;                  // 0..3071
    int c = idx >> 4, t4 = idx & 15;
    *(ushort4*)(ymat + c*68 + t4*4) = *(const ushort4*)(ysrc + c*64 + t4*4);
  }
  __syncthreads();

  // ---- LN stats: thread (tok = tid&63, part = tid>>6) sums 48 channels
  {
    int tok = tid & 63, part = tid >> 6;
    float S = 0.f, Q = 0.f;
    #pragma unroll
    for (int j = 0; j < 48; ++j) {
      float v = bf2f(ymat[(part*48 + j)*68 + tok]);
      S += v; Q = fmaf(v, v, Q);
    }
    sred[0][part][tok] = S; sred[1][part][tok] = Q;
  }
  __syncthreads();
  if (tid < 64) {
    float S = sred[0][0][tid] + sred[0][1][tid] + sred[0][2][tid] + sred[0][3][tid];
    float Q = sred[1][0][tid] + sred[1][1][tid] + sred[1][2][tid] + sred[1][3][tid];
    float m = S*(1.f/192.f);
    float var = Q*(1.f/192.f) - m*m;
    murs[0][tid] = m;
    murs[1][tid] = rsqrtf(var + 1e-6f);
  }
  __syncthreads();

  // ---- build A-fragments into aFrag (6 frags/thread, b128 coalesced writes)
  #pragma unroll
  for (int k = 0; k < 6; ++k) {
    int fi = tid + 256*k;                   // 0..1535
    int lane2 = fi & 63, rest = fi >> 6;
    int mt = rest / 6, ks = rest - mt*6;
    int tok = mt*16 + (lane2 & 15);
    int cc0 = ks*32 + (lane2 >> 4)*8;
    float m = murs[0][tok], rs = murs[1][tok];
    f4v lw0 = *(const f4v*)(ln_w + cc0), lw1 = *(const f4v*)(ln_w + cc0 + 4);
    f4v lb0 = *(const f4v*)(ln_b + cc0), lb1 = *(const f4v*)(ln_b + cc0 + 4);
    union { bf8v v; unsigned short u[8]; } pk;
    #pragma unroll
    for (int j = 0; j < 4; ++j) {
      float v0 = (bf2f(ymat[(cc0+j)*68 + tok])   - m)*rs*lw0[j] + lb0[j];
      float v1 = (bf2f(ymat[(cc0+4+j)*68 + tok]) - m)*rs*lw1[j] + lb1[j];
      pk.u[j] = f2bf(v0); pk.u[4+j] = f2bf(v1);
    }
    *(bf8v*)(aFrag + fi*8) = pk.v;
  }
  __syncthreads();                          // aFrag ready; ymat dead

  f4v acc2[4][3];
  #pragma unroll
  for (int mt = 0; mt < 4; ++mt)
    #pragma unroll
    for (int nt = 0; nt < 3; ++nt)
      acc2[mt][nt] = (f4v){0.f, 0.f, 0.f, 0.f};

  // ---- pipelined B fragment pointers (ushort units)
  const unsigned short* p1base = b1f + wave*2*3072 + lane*8;   // + ch*24576
  const unsigned short* p2base = b2f + wave*3*12288 + lane*8;  // + ch*2048

  bf8v B1r[12];
  #pragma unroll
  for (int i = 0; i < 12; ++i) {            // preload B1 for ch=0
    int jj = i / 6, ks = i - jj*6;
    B1r[i] = *(const bf8v*)(p1base + jj*3072 + ks*512);
  }

  #pragma unroll 1                          // keep body in I-cache
  for (int ch = 0; ch < 6; ++ch) {
    // ---- B2r(ch): 12 outstanding loads, drain covered by GEMM1
    bf8v B2r[12];
    const unsigned short* p2 = p2base + ch*2048;
    #pragma unroll
    for (int ks2 = 0; ks2 < 4; ++ks2)
      #pragma unroll
      for (int nt = 0; nt < 3; ++nt)
        B2r[ks2*3 + nt] = *(const bf8v*)(p2 + nt*12288 + ks2*512);

    // ---- GEMM1: A from LDS, B1 from regs
    f4v a1[2][4];
    #pragma unroll
    for (int jj = 0; jj < 2; ++jj)
      #pragma unroll
      for (int mt = 0; mt < 4; ++mt) a1[jj][mt] = (f4v){0.f,0.f,0.f,0.f};
    #pragma unroll
    for (int ks = 0; ks < 6; ++ks) {
      bf8v Af[4];
      #pragma unroll
      for (int mt = 0; mt < 4; ++mt)
        Af[mt] = *(const bf8v*)(aFrag + ((mt*6 + ks)*64 + lane)*8);
      #pragma unroll
      for (int jj = 0; jj < 2; ++jj)
        #pragma unroll
        for (int mt = 0; mt < 4; ++mt)
          a1[jj][mt] = __builtin_amdgcn_mfma_f32_16x16x32_bf16(Af[mt], B1r[jj*6+ks], a1[jj][mt], 0, 0, 0);
    }

    // ---- prefetch B1r(ch+1): drain covered by gelu + barrier + GEMM2
    if (ch < 5) {
      const unsigned short* p1 = p1base + (ch+1)*24576;
      #pragma unroll
      for (int i = 0; i < 12; ++i) {
        int jj = i / 6, ks = i - jj*6;
        B1r[i] = *(const bf8v*)(p1 + jj*3072 + ks*512);
      }
    }

    // ---- bias + gelu -> hbuf (A2-frag order)
    #pragma unroll
    for (int jj = 0; jj < 2; ++jj) {
      float b1v = b1[(ch*8 + wave*2 + jj)*16 + ln15];
      int lane_hi = jj*2 + (ln15 >> 3);
      #pragma unroll
      for (int mt = 0; mt < 4; ++mt)
        #pragma unroll
        for (int rr = 0; rr < 4; ++rr) {
          float g = gelu_f(a1[jj][mt][rr] + b1v);
          int elem = ((mt*4 + wave)*64 + lane_hi*16 + (lq*4 + rr))*8 + (lane & 7);
          hbuf[elem] = f2bf(g);
        }
    }
    __syncthreads();
    // ---- GEMM2 partial: acc2 += h_chunk @ w2[ch*128.., :]
    #pragma unroll
    for (int ks2 = 0; ks2 < 4; ++ks2) {
      bf8v A2[4];
      #pragma unroll
      for (int mt = 0; mt < 4; ++mt)
        A2[mt] = *(const bf8v*)(hbuf + ((mt*4 + ks2)*64 + lane)*8);
      #pragma unroll
      for (int nt = 0; nt < 3; ++nt)
        #pragma unroll
        for (int mt = 0; mt < 4; ++mt)
          acc2[mt][nt] = __builtin_amdgcn_mfma_f32_16x16x32_bf16(A2[mt], B2r[ks2*3+nt], acc2[mt][nt], 0, 0, 0);
    }
    __syncthreads();                        // hbuf reused next ch
  }

  // ---- epilogue: gamma*(acc+b2), f4v store channels-first
  #pragma unroll
  for (int nt = 0; nt < 3; ++nt) {
    int c = (wave*3 + nt)*16 + ln15;
    float gm = gamma[c], bb = b2[c];
    size_t cbase = ((size_t)(b*CCH + c))*NPOS + (size_t)(y0 + lq)*32 + x0;
    #pragma unroll
    for (int mt = 0; mt < 4; ++mt) {
      f4v o;
      o[0] = gm*(acc2[mt][nt][0] + bb);
      o[1] = gm*(acc2[mt][nt][1] + bb);
      o[2] = gm*(acc2[mt][nt][2] + bb);
      o[3] = gm*(acc2[mt][nt][3] + bb);
      *(f4v*)(out + cbase + (size_t)(z0 + mt)*1024) = o;
    }
  }
}

// ---------------------------------------------------------------------------
extern "C" void kernel_launch(void* const* d_in, const int* in_sizes, int n_in,
                              void* d_out, int out_size, void* d_ws, size_t ws_size,
                              hipStream_t stream) {
  const float* x     = (const float*)d_in[0];
  const int*   mask  = (const int*)  d_in[1];
  const float* dw_w  = (const float*)d_in[2];
  const float* dw_b  = (const float*)d_in[3];
  const float* ln_w  = (const float*)d_in[4];
  const float* ln_b  = (const float*)d_in[5];
  const float* w1    = (const float*)d_in[6];
  const float* b1    = (const float*)d_in[7];
  const float* w2    = (const float*)d_in[8];
  const float* b2    = (const float*)d_in[9];
  const float* gamma = (const float*)d_in[10];
  float* out = (float*)d_out;
  char* ws = (char*)d_ws;

  unsigned short* yc  = (unsigned short*)(ws + WS_Y);
  unsigned short* b1f = (unsigned short*)(ws + WS_B1F);
  unsigned short* b2f = (unsigned short*)(ws + WS_B2F);
  unsigned int*   wpf = (unsigned int*)(ws + WS_WPF);

  bool wp_ok = ws_size >= WS_TOTAL;
  int prep_grid = wp_ok ? 181 : 144;        // 181 covers the wpf branch
  prep_w_kernel<<<prep_grid, 256, 0, stream>>>(w1, w2, dw_w, b1f, b2f, wpf);
  if (wp_ok)
    conv_dw_f16_kernel<<<3072, 256, 0, stream>>>(x, dw_b, wpf, yc);
  else
    conv_dw_f32_kernel<<<3072, 256, 0, stream>>>(x, dw_w, dw_b, yc);
  mlp_kernel<<<1024, 256, 0, stream>>>(yc, b1f, b2f, b1, b2, gamma, ln_w, ln_b, mask, out);
}

// Round 7
// 238.828 us; speedup vs baseline: 1.1822x; 1.1318x over previous
//
#include <hip/hip_runtime.h>
#include <hip/hip_bf16.h>

typedef __attribute__((ext_vector_type(2))) float f2v;
typedef __attribute__((ext_vector_type(4))) float f4v;
typedef __attribute__((ext_vector_type(8))) short bf8v;
typedef __attribute__((ext_vector_type(8))) _Float16 h8v;

// ---- problem constants ----
#define NPOS 32768            // 32*32*32
#define CCH  192
#define HID  768

// ---- workspace layout (bytes) ----
#define WS_Y    ((size_t)0)           // 25,165,824  conv out bf16, cell layout
#define WS_B1F  ((size_t)25165824)    // 294,912  w1 bf16 B-frag swizzled
#define WS_B2F  ((size_t)25460736)    // 294,912  w2 bf16 B-frag swizzled
#define WS_WPF  ((size_t)25755648)    // 301,056  f16 dot2 weight pairs (fallback tier)
#define WS_B3F  ((size_t)26056704)    // 9,633,792  conv Toeplitz B-frags f16 (192*49 x 1KB)
#define WS_TOTAL_MFMA ((size_t)35690496)
#define WS_TOTAL_DOT2 ((size_t)26056704)

__device__ inline unsigned short f2bf(float f){
  unsigned int u = __float_as_uint(f);
  u += 0x7FFFu + ((u >> 16) & 1u);      // RNE
  return (unsigned short)(u >> 16);
}
__device__ inline float bf2f(unsigned short s){
  return __uint_as_float(((unsigned int)s) << 16);
}
__device__ inline float gelu_f(float x){
  float u = 0.7978845608028654f * x * fmaf(0.044715f, x*x, 1.0f);
  float e = __expf(2.0f*u);
  float th = __fdividef(e - 1.0f, e + 1.0f);
  return 0.5f*x*(1.0f + th);
}

#define DOT2(A, X, W) \
  asm("v_dot2_f32_f16 %0, %1, %2, %0" : "+v"(A) : "v"(X), "s"(W))

// ---------------------------------------------------------------------------
// Kernel 1 (main): depthwise 7x7x7 conv + bias as implicit GEMM on MFMA (f16).
// Block = (b, c, 16x16 xy quadrant, 16-z half), 4 waves; wave w owns output
// y rows {4w..4w+3}, each a 16(z=m) x 16(x=n) MFMA tile.
// Per tap (kz,ky): out[m][n] += sum_k A[m][k]*B[k][n] with
//   A[m][k] = in_f16[z tile row m+kz][y row 4w+t+ky][LDS col k] (col0 = tx0-4)
//   B[k][n] = w[kz][ky][k-n-1] for 1<=k-n<=7 else 0  (precomputed f16 B-frags)
// A-frag: m=lane&15, k=(lane>>4)*8+j. C-frag: col(n)=lane&15, row(m)=q*4+r.
// LDS tile [lz 22][ly 22][col 32] f16, z-stride ZSTR=712 halves: byte z-stride
// 1424 == 16 (mod 128) so 8 consecutive lanes hit disjoint bank phases.
// Cols 24..31 zeroed (B band is zero there; guards 0*NaN). 49 taps accumulate
// in f32 C. B-frags 1-deep prefetched (tap+1 issued before tap's 4 MFMAs).
// Output: bf16 cell-blocked yc[((b*512+cell)*192+c)*64 + tok], tok=dz*16+dy*4+dx.
// ---------------------------------------------------------------------------
#define ZSTR 712
__global__ __launch_bounds__(256) void conv_mfma_kernel(
    const float* __restrict__ x, const float* __restrict__ dw_b,
    const unsigned short* __restrict__ b3f, unsigned short* __restrict__ yc)
{
  __shared__ unsigned short tile[22*ZSTR];    // 31,328 B

  int bid = blockIdx.x;                // 3072 = 192c * 16(r)
  int c = bid % 192;
  int r = bid / 192;                   // 0..15
  int xq = r & 1, yq = (r >> 1) & 1, zh = (r >> 2) & 1, b = r >> 3;
  int tx0 = xq*16, ty0 = yq*16, zb = zh*16;

  int tid = threadIdx.x;
  const float* xsrc = x + ((size_t)(b*CCH + c))*NPOS;

  // ---- stage input: 22z x 22y x 24 real cols (f32->f16), cols 24..31 zero
  #pragma unroll
  for (int it = 0; it < 8; ++it) {
    int idx = tid + 256*it;            // 0..1935 (22*22*4 chunks of 8 halves)
    if (idx < 1936) {
      int ci = idx & 3;
      int row = idx >> 2;
      int lz = row / 22, ly = row - lz*22;
      int gz = zb - 3 + lz, gy = ty0 - 3 + ly;
      f4v v0 = {0.f,0.f,0.f,0.f}, v1 = {0.f,0.f,0.f,0.f};
      if (((unsigned)gz < 32u) & ((unsigned)gy < 32u) & (ci < 3)) {
        int gx0 = tx0 - 4 + 8*ci;
        const float* src = xsrc + (size_t)gz*1024 + gy*32;
        if ((unsigned)gx0 <= 28u)     v0 = *(const f4v*)(src + gx0);
        if ((unsigned)(gx0+4) <= 28u) v1 = *(const f4v*)(src + gx0 + 4);
      }
      h8v pk;
      pk[0] = (_Float16)v0[0]; pk[1] = (_Float16)v0[1];
      pk[2] = (_Float16)v0[2]; pk[3] = (_Float16)v0[3];
      pk[4] = (_Float16)v1[0]; pk[5] = (_Float16)v1[1];
      pk[6] = (_Float16)v1[2]; pk[7] = (_Float16)v1[3];
      *(h8v*)(tile + lz*ZSTR + ly*32 + ci*8) = pk;
    }
  }
  __syncthreads();

  int wv = tid >> 6, lane = tid & 63;
  int q = lane >> 4, zm = lane & 15;   // A-frag: m=zm (z), k-group q

  const unsigned short* abase = tile + (size_t)zm*ZSTR + q*8;
  const unsigned short* bbase = b3f + ((size_t)c*49)*512 + (size_t)lane*8;

  f4v acc[4];
  #pragma unroll
  for (int t = 0; t < 4; ++t) acc[t] = (f4v){0.f,0.f,0.f,0.f};

  h8v Bc = *(const h8v*)(bbase);       // tap 0
  #pragma unroll 1
  for (int kz = 0; kz < 7; ++kz) {
    h8v Af[10];                        // rows ly = 4w+0 .. 4w+9, reused over ky
    #pragma unroll
    for (int rr = 0; rr < 10; ++rr)
      Af[rr] = *(const h8v*)(abase + kz*ZSTR + (4*wv + rr)*32);
    #pragma unroll
    for (int ky = 0; ky < 7; ++ky) {
      int tap = kz*7 + ky;
      int tnx = (tap < 48) ? tap + 1 : 48;     // clamp: never read past b3f row
      h8v Bn = *(const h8v*)(bbase + (size_t)tnx*512);
      acc[0] = __builtin_amdgcn_mfma_f32_16x16x32_f16(Af[ky+0], Bc, acc[0], 0, 0, 0);
      acc[1] = __builtin_amdgcn_mfma_f32_16x16x32_f16(Af[ky+1], Bc, acc[1], 0, 0, 0);
      acc[2] = __builtin_amdgcn_mfma_f32_16x16x32_f16(Af[ky+2], Bc, acc[2], 0, 0, 0);
      acc[3] = __builtin_amdgcn_mfma_f32_16x16x32_f16(Af[ky+3], Bc, acc[3], 0, 0, 0);
      Bc = Bn;
    }
  }

  // ---- store: C col=lane&15 -> ox, row=q*4+r -> oz; tok = dz*16 + dy*4 + dx
  float bias = dw_b[c];
  int cz = zh*4 + q;                   // oz = zh*16 + q*4 + r -> cz = zh*4+q, dz=r
  int cx = (tx0 >> 2) + (zm >> 2);     // ox = tx0 + zm
  int xr = zm & 3;
  int cy = (ty0 >> 2) + wv;            // oy = ty0 + 4*wv + t -> dy = t
  int cell = cz*64 + cy*8 + cx;
  unsigned short* yb0 = yc + (((size_t)(b*512 + cell))*192 + c)*64 + xr;
  #pragma unroll
  for (int t = 0; t < 4; ++t) {
    unsigned short* yb = yb0 + t*4;
    yb[0]  = f2bf(acc[t][0] + bias);
    yb[16] = f2bf(acc[t][1] + bias);
    yb[32] = f2bf(acc[t][2] + bias);
    yb[48] = f2bf(acc[t][3] + bias);
  }
}

// ---------------------------------------------------------------------------
// Kernel 1 (tier-2 fallback): dot2 f16 path (round-5 kernel).
// ---------------------------------------------------------------------------
__global__ __launch_bounds__(256, 6) void conv_dw_f16_kernel(
    const float* __restrict__ x, const float* __restrict__ dw_b,
    const unsigned int* __restrict__ wpf, unsigned short* __restrict__ yc)
{
  __shared__ unsigned short ring[22*528];

  int bid = blockIdx.x;
  int c = bid % 192;
  int r = bid / 192;
  int xq = r & 1, yq = (r >> 1) & 1, zh = (r >> 2) & 1, b = r >> 3;
  int tx0 = xq*16, ty0 = yq*16, zb = zh*16;

  int tid = threadIdx.x;
  const float* xsrc = x + ((size_t)(b*CCH + c))*NPOS;

  for (int idx = tid; idx < 2904; idx += 256) {
    int sl = idx / 132;
    int rem = idx - sl*132;
    int rr = rem / 6, ci = rem - rr*6;
    int zi = zb - 3 + sl, gy = ty0 - 3 + rr, gx = tx0 - 4 + 4*ci;
    f4v v = {0.f, 0.f, 0.f, 0.f};
    if ((unsigned)zi < 32u && (unsigned)gy < 32u && (unsigned)gx <= 28u)
      v = *(const f4v*)(xsrc + (size_t)zi*1024 + gy*32 + gx);
    union { _Float16 h[4]; uint2 u2; } pk;
    pk.h[0] = (_Float16)v[0]; pk.h[1] = (_Float16)v[1];
    pk.h[2] = (_Float16)v[2]; pk.h[3] = (_Float16)v[3];
    *(uint2*)(ring + sl*528 + rr*24 + ci*4) = pk.u2;
  }
  __syncthreads();

  int p = tid & 15, zl = tid >> 4;
  int px = p & 3, py = p >> 2;
  int y0 = py*4, px4 = px*4;
  const unsigned short* base = ring + zl*528 + y0*24 + px4;
  const unsigned int* wb = wpf + (size_t)c*392;

  float acc[4][4];
  #pragma unroll
  for (int i = 0; i < 4; ++i)
    #pragma unroll
    for (int j = 0; j < 4; ++j) acc[i][j] = 0.f;

  #pragma unroll 1
  for (int s = 0; s < 7; ++s) {
    const unsigned short* sb = base + s*528;
    const unsigned int* wrow = wb + s*56;
    #pragma unroll
    for (int rr = 0; rr < 10; ++rr) {
      const unsigned short* rb = sb + rr*24;
      uint2 q0 = *(const uint2*)(rb);
      uint2 q1 = *(const uint2*)(rb + 4);
      uint2 q2 = *(const uint2*)(rb + 8);
      unsigned int D[6] = {q0.x, q0.y, q1.x, q1.y, q2.x, q2.y};
      #pragma unroll
      for (int dy = 0; dy < 4; ++dy) {
        int ky = rr - dy;
        if (ky < 0 || ky > 6) continue;
        const unsigned int* wk = wrow + ky*8;
        #pragma unroll
        for (int t = 0; t < 4; ++t) {
          DOT2(acc[dy][0], D[t],   wk[t]);
          DOT2(acc[dy][1], D[t+1], wk[4+t]);
          DOT2(acc[dy][2], D[t+1], wk[t]);
          DOT2(acc[dy][3], D[t+2], wk[4+t]);
        }
      }
    }
  }

  float bias = dw_b[c];
  int z = zb + zl;
  int cz = z >> 2, cx = (tx0 >> 2) + px, cy = (ty0 >> 2) + py;
  int cell = cz*64 + cy*8 + cx;
  unsigned short* ybase = yc + (((size_t)(b*512 + cell))*192 + c)*64;
  int tokz = (z & 3)*16;
  #pragma unroll
  for (int dy = 0; dy < 4; ++dy) {
    ushort4 o;
    o.x = f2bf(acc[dy][0] + bias);
    o.y = f2bf(acc[dy][1] + bias);
    o.z = f2bf(acc[dy][2] + bias);
    o.w = f2bf(acc[dy][3] + bias);
    *(ushort4*)(ybase + tokz + dy*4) = o;
  }
}

// ---------------------------------------------------------------------------
// Kernel 1 (tier-3 fallback): fp32 C path.
// ---------------------------------------------------------------------------
__global__ __launch_bounds__(256) void conv_dw_f32_kernel(
    const float* __restrict__ x, const float* __restrict__ dw_w,
    const float* __restrict__ dw_b, unsigned short* __restrict__ yc)
{
  __shared__ float ring[22*528];

  int bid = blockIdx.x;
  int c = bid % 192;
  int r = bid / 192;
  int xq = r & 1, yq = (r >> 1) & 1, zh = (r >> 2) & 1, b = r >> 3;
  int tx0 = xq*16, ty0 = yq*16, zb = zh*16;

  int tid = threadIdx.x;
  const float* xsrc = x + ((size_t)(b*CCH + c))*NPOS;

  for (int idx = tid; idx < 2904; idx += 256) {
    int sl = idx / 132;
    int rem = idx - sl*132;
    int rr = rem / 6, ci = rem - rr*6;
    int zi = zb - 3 + sl, gy = ty0 - 3 + rr, gx = tx0 - 4 + 4*ci;
    f4v v = {0.f, 0.f, 0.f, 0.f};
    if ((unsigned)zi < 32u && (unsigned)gy < 32u && (unsigned)gx <= 28u)
      v = *(const f4v*)(xsrc + (size_t)zi*1024 + gy*32 + gx);
    *(f4v*)(ring + sl*528 + rr*24 + ci*4) = v;
  }
  __syncthreads();

  int p = tid & 15, zl = tid >> 4;
  int px = p & 3, py = p >> 2;
  int y0 = py*4, px4 = px*4;
  const float* base = ring + zl*528 + y0*24 + px4;
  const float* wbase = dw_w + (size_t)c*343;

  f2v acc[8];
  #pragma unroll
  for (int i = 0; i < 8; ++i) acc[i] = (f2v){0.f, 0.f};

  #pragma unroll 1
  for (int s = 0; s < 7; ++s) {
    const float* sb = base + s*528;
    f4v n0 = *(const f4v*)(sb);
    f4v n1 = *(const f4v*)(sb + 4);
    f4v n2 = *(const f4v*)(sb + 8);
    #pragma unroll
    for (int rr = 0; rr < 10; ++rr) {
      f4v r0 = n0, r1 = n1, r2 = n2;
      if (rr < 9) {
        n0 = *(const f4v*)(sb + (rr+1)*24);
        n1 = *(const f4v*)(sb + (rr+1)*24 + 4);
        n2 = *(const f4v*)(sb + (rr+1)*24 + 8);
      }
      f2v pr[10];
      pr[1] = (f2v){r0[1], r0[2]};
      pr[2] = (f2v){r0[2], r0[3]};
      pr[3] = (f2v){r0[3], r1[0]};
      pr[4] = (f2v){r1[0], r1[1]};
      pr[5] = (f2v){r1[1], r1[2]};
      pr[6] = (f2v){r1[2], r1[3]};
      pr[7] = (f2v){r1[3], r2[0]};
      pr[8] = (f2v){r2[0], r2[1]};
      pr[9] = (f2v){r2[1], r2[2]};
      #pragma unroll
      for (int dy = 0; dy < 4; ++dy) {
        int ky = rr - dy;
        if (ky < 0 || ky > 6) continue;
        #pragma unroll
        for (int kx = 0; kx < 7; ++kx) {
          float w = wbase[s*49 + ky*7 + kx];
          f2v wv = (f2v){w, w};
          acc[dy*2+0] = __builtin_elementwise_fma(wv, pr[kx+1], acc[dy*2+0]);
          acc[dy*2+1] = __builtin_elementwise_fma(wv, pr[kx+3], acc[dy*2+1]);
        }
      }
    }
  }

  float bias = dw_b[c];
  int z = zb + zl;
  int cz = z >> 2, cx = (tx0 >> 2) + px, cy = (ty0 >> 2) + py;
  int cell = cz*64 + cy*8 + cx;
  unsigned short* ybase = yc + (((size_t)(b*512 + cell))*192 + c)*64;
  int tokz = (z & 3)*16;
  #pragma unroll
  for (int dy = 0; dy < 4; ++dy) {
    ushort4 o;
    o.x = f2bf(acc[dy*2+0][0] + bias);
    o.y = f2bf(acc[dy*2+0][1] + bias);
    o.z = f2bf(acc[dy*2+1][0] + bias);
    o.w = f2bf(acc[dy*2+1][1] + bias);
    *(ushort4*)(ybase + tokz + dy*4) = o;
  }
}

// ---------------------------------------------------------------------------
// Kernel 2: weight prep. w1/w2 -> bf16 MFMA-B-frag; dw_w -> dot2 pairs (tier2)
// and f16 Toeplitz conv B-frags (tier1):
//   b3f[frag=c*49+kz*7+ky][lane][j] = f16(w[kz][ky][k-n-1]), k=(lane>>4)*8+j,
//   n=lane&15, zero outside 0<=k-n-1<=6.
// ---------------------------------------------------------------------------
__global__ __launch_bounds__(256) void prep_w_kernel(
    const float* __restrict__ w1, const float* __restrict__ w2,
    const float* __restrict__ dw_w,
    unsigned short* __restrict__ b1f, unsigned short* __restrict__ b2f,
    unsigned int* __restrict__ wpf, unsigned short* __restrict__ b3f)
{
  int gid = blockIdx.x*256 + threadIdx.x;
  if (gid < 18432) {
    int fi = gid;                         // w1 (C=192 x HID=768)
    int lane = fi & 63, fr = fi >> 6;
    int nt = fr / 6, ks = fr - nt*6;
    int n  = nt*16 + (lane & 15);
    int kb = ks*32 + (lane >> 4)*8;
    #pragma unroll
    for (int j = 0; j < 8; ++j) b1f[fi*8 + j] = f2bf(w1[(kb+j)*HID + n]);
  } else if (gid < 36864) {
    int fi = gid - 18432;                 // w2 (HID=768 x C=192)
    int lane = fi & 63, fr = fi >> 6;
    int nt = fr / 24, ks = fr - nt*24;
    int n  = nt*16 + (lane & 15);
    int kb = ks*32 + (lane >> 4)*8;
    #pragma unroll
    for (int j = 0; j < 8; ++j) b2f[fi*8 + j] = f2bf(w2[(kb+j)*CCH + n]);
  } else if (gid < 46272) {
    int ci = gid - 36864;                 // 192*49 dot2 rows (tier-2)
    int cch = ci / 49, t7 = ci - cch*49;
    const float* wr = dw_w + cch*343 + t7*7;
    float w[8];
    #pragma unroll
    for (int j = 0; j < 7; ++j) w[j] = wr[j];
    w[7] = 0.f;
    union { _Float16 h[2]; unsigned int u; } pk;
    #pragma unroll
    for (int t = 0; t < 4; ++t) {
      pk.h[0] = (t == 0) ? (_Float16)0.f : (_Float16)w[2*t-1];
      pk.h[1] = (_Float16)w[2*t];
      wpf[ci*8 + t] = pk.u;
    }
    #pragma unroll
    for (int t = 0; t < 4; ++t) {
      pk.h[0] = (_Float16)w[2*t];
      pk.h[1] = (_Float16)w[2*t+1];
      wpf[ci*8 + 4 + t] = pk.u;
    }
  } else if (gid < 648384) {
    int fi = gid - 46272;                 // 9408 frags x 64 lanes
    int lane = fi & 63, frag = fi >> 6;
    int cch = frag / 49, tap = frag - cch*49;
    const float* wr = dw_w + cch*343 + tap*7;
    int q = lane >> 4, n = lane & 15;
    h8v pk;
    #pragma unroll
    for (int j = 0; j < 8; ++j) {
      int t = q*8 + j - n - 1;
      pk[j] = (t >= 0 && t <= 6) ? (_Float16)wr[t] : (_Float16)0.f;
    }
    *(h8v*)(b3f + (size_t)fi*8) = pk;
  }
}

// ---------------------------------------------------------------------------
// Kernel 3: fused LN + MLP per active cell (unchanged this round).
// ---------------------------------------------------------------------------
__global__ __launch_bounds__(256) void mlp_kernel(
    const unsigned short* __restrict__ yc, const unsigned short* __restrict__ b1f,
    const unsigned short* __restrict__ b2f, const float* __restrict__ b1,
    const float* __restrict__ b2, const float* __restrict__ gamma,
    const float* __restrict__ ln_w, const float* __restrict__ ln_b,
    const int* __restrict__ mask, float* __restrict__ out)
{
  int bid = blockIdx.x;
  int b = bid >> 9, cell = bid & 511;
  int cz = cell >> 6, cy = (cell >> 3) & 7, cx = cell & 7;
  int z0 = cz*4, y0 = cy*4, x0 = cx*4;
  int tid = threadIdx.x, wave = tid >> 6, lane = tid & 63;
  int lq = lane >> 4, ln15 = lane & 15;

  if (mask[bid] == 0) {
    f4v z4 = {0.f, 0.f, 0.f, 0.f};
    #pragma unroll
    for (int pp = 0; pp < 12; ++pp) {
      int i4 = tid + 256*pp;
      int c = i4 >> 4, rem = i4 & 15;
      int dz = rem >> 2, dy = rem & 3;
      *(f4v*)(out + ((size_t)(b*CCH + c))*NPOS
                  + (size_t)(z0+dz)*1024 + (y0+dy)*32 + x0) = z4;
    }
    return;
  }

  __shared__ __align__(16) char uni[26112];
  unsigned short* ymat = (unsigned short*)uni;
  unsigned short* hbuf = (unsigned short*)uni;
  __shared__ unsigned short aFrag[12288];
  __shared__ float sred[2][4][64];
  __shared__ float murs[2][64];

  const unsigned short* ysrc = yc + (size_t)bid*12288;

  #pragma unroll
  for (int k = 0; k < 12; ++k) {
    int idx = tid + 256*k;
    int c = idx >> 4, t4 = idx & 15;
    *(ushort4*)(ymat + c*68 + t4*4) = *(const ushort4*)(ysrc + c*64 + t4*4);
  }
  __syncthreads();

  {
    int tok = tid & 63, part = tid >> 6;
    float S = 0.f, Q = 0.f;
    #pragma unroll
    for (int j = 0; j < 48; ++j) {
      float v = bf2f(ymat[(part*48 + j)*68 + tok]);
      S += v; Q = fmaf(v, v, Q);
    }
    sred[0][part][tok] = S; sred[1][part][tok] = Q;
  }
  __syncthreads();
  if (tid < 64) {
    float S = sred[0][0][tid] + sred[0][1][tid] + sred[0][2][tid] + sred[0][3][tid];
    float Q = sred[1][0][tid] + sred[1][1][tid] + sred[1][2][tid] + sred[1][3][tid];
    float m = S*(1.f/192.f);
    float var = Q*(1.f/192.f) - m*m;
    murs[0][tid] = m;
    murs[1][tid] = rsqrtf(var + 1e-6f);
  }
  __syncthreads();

  #pragma unroll
  for (int k = 0; k < 6; ++k) {
    int fi = tid + 256*k;
    int lane2 = fi & 63, rest = fi >> 6;
    int mt = rest / 6, ks = rest - mt*6;
    int tok = mt*16 + (lane2 & 15);
    int cc0 = ks*32 + (lane2 >> 4)*8;
    float m = murs[0][tok], rs = murs[1][tok];
    f4v lw0 = *(const f4v*)(ln_w + cc0), lw1 = *(const f4v*)(ln_w + cc0 + 4);
    f4v lb0 = *(const f4v*)(ln_b + cc0), lb1 = *(const f4v*)(ln_b + cc0 + 4);
    union { bf8v v; unsigned short u[8]; } pk;
    #pragma unroll
    for (int j = 0; j < 4; ++j) {
      float v0 = (bf2f(ymat[(cc0+j)*68 + tok])   - m)*rs*lw0[j] + lb0[j];
      float v1 = (bf2f(ymat[(cc0+4+j)*68 + tok]) - m)*rs*lw1[j] + lb1[j];
      pk.u[j] = f2bf(v0); pk.u[4+j] = f2bf(v1);
    }
    *(bf8v*)(aFrag + fi*8) = pk.v;
  }
  __syncthreads();

  f4v acc2[4][3];
  #pragma unroll
  for (int mt = 0; mt < 4; ++mt)
    #pragma unroll
    for (int nt = 0; nt < 3; ++nt)
      acc2[mt][nt] = (f4v){0.f, 0.f, 0.f, 0.f};

  const unsigned short* p1base = b1f + wave*2*3072 + lane*8;
  const unsigned short* p2base = b2f + wave*3*12288 + lane*8;

  bf8v B1r[12];
  #pragma unroll
  for (int i = 0; i < 12; ++i) {
    int jj = i / 6, ks = i - jj*6;
    B1r[i] = *(const bf8v*)(p1base + jj*3072 + ks*512);
  }

  #pragma unroll 1
  for (int ch = 0; ch < 6; ++ch) {
    bf8v B2r[12];
    const unsigned short* p2 = p2base + ch*2048;
    #pragma unroll
    for (int ks2 = 0; ks2 < 4; ++ks2)
      #pragma unroll
      for (int nt = 0; nt < 3; ++nt)
        B2r[ks2*3 + nt] = *(const bf8v*)(p2 + nt*12288 + ks2*512);

    f4v a1[2][4];
    #pragma unroll
    for (int jj = 0; jj < 2; ++jj)
      #pragma unroll
      for (int mt = 0; mt < 4; ++mt) a1[jj][mt] = (f4v){0.f,0.f,0.f,0.f};
    #pragma unroll
    for (int ks = 0; ks < 6; ++ks) {
      bf8v Af[4];
      #pragma unroll
      for (int mt = 0; mt < 4; ++mt)
        Af[mt] = *(const bf8v*)(aFrag + ((mt*6 + ks)*64 + lane)*8);
      #pragma unroll
      for (int jj = 0; jj < 2; ++jj)
        #pragma unroll
        for (int mt = 0; mt < 4; ++mt)
          a1[jj][mt] = __builtin_amdgcn_mfma_f32_16x16x32_bf16(Af[mt], B1r[jj*6+ks], a1[jj][mt], 0, 0, 0);
    }

    if (ch < 5) {
      const unsigned short* p1 = p1base + (ch+1)*24576;
      #pragma unroll
      for (int i = 0; i < 12; ++i) {
        int jj = i / 6, ks = i - jj*6;
        B1r[i] = *(const bf8v*)(p1 + jj*3072 + ks*512);
      }
    }

    #pragma unroll
    for (int jj = 0; jj < 2; ++jj) {
      float b1v = b1[(ch*8 + wave*2 + jj)*16 + ln15];
      int lane_hi = jj*2 + (ln15 >> 3);
      #pragma unroll
      for (int mt = 0; mt < 4; ++mt)
        #pragma unroll
        for (int rr = 0; rr < 4; ++rr) {
          float g = gelu_f(a1[jj][mt][rr] + b1v);
          int elem = ((mt*4 + wave)*64 + lane_hi*16 + (lq*4 + rr))*8 + (lane & 7);
          hbuf[elem] = f2bf(g);
        }
    }
    __syncthreads();
    #pragma unroll
    for (int ks2 = 0; ks2 < 4; ++ks2) {
      bf8v A2[4];
      #pragma unroll
      for (int mt = 0; mt < 4; ++mt)
        A2[mt] = *(const bf8v*)(hbuf + ((mt*4 + ks2)*64 + lane)*8);
      #pragma unroll
      for (int nt = 0; nt < 3; ++nt)
        #pragma unroll
        for (int mt = 0; mt < 4; ++mt)
          acc2[mt][nt] = __builtin_amdgcn_mfma_f32_16x16x32_bf16(A2[mt], B2r[ks2*3+nt], acc2[mt][nt], 0, 0, 0);
    }
    __syncthreads();
  }

  #pragma unroll
  for (int nt = 0; nt < 3; ++nt) {
    int c = (wave*3 + nt)*16 + ln15;
    float gm = gamma[c], bb = b2[c];
    size_t cbase = ((size_t)(b*CCH + c))*NPOS + (size_t)(y0 + lq)*32 + x0;
    #pragma unroll
    for (int mt = 0; mt < 4; ++mt) {
      f4v o;
      o[0] = gm*(acc2[mt][nt][0] + bb);
      o[1] = gm*(acc2[mt][nt][1] + bb);
      o[2] = gm*(acc2[mt][nt][2] + bb);
      o[3] = gm*(acc2[mt][nt][3] + bb);
      *(f4v*)(out + cbase + (size_t)(z0 + mt)*1024) = o;
    }
  }
}

// ---------------------------------------------------------------------------
extern "C" void kernel_launch(void* const* d_in, const int* in_sizes, int n_in,
                              void* d_out, int out_size, void* d_ws, size_t ws_size,
                              hipStream_t stream) {
  const float* x     = (const float*)d_in[0];
  const int*   mask  = (const int*)  d_in[1];
  const float* dw_w  = (const float*)d_in[2];
  const float* dw_b  = (const float*)d_in[3];
  const float* ln_w  = (const float*)d_in[4];
  const float* ln_b  = (const float*)d_in[5];
  const float* w1    = (const float*)d_in[6];
  const float* b1    = (const float*)d_in[7];
  const float* w2    = (const float*)d_in[8];
  const float* b2    = (const float*)d_in[9];
  const float* gamma = (const float*)d_in[10];
  float* out = (float*)d_out;
  char* ws = (char*)d_ws;

  unsigned short* yc  = (unsigned short*)(ws + WS_Y);
  unsigned short* b1f = (unsigned short*)(ws + WS_B1F);
  unsigned short* b2f = (unsigned short*)(ws + WS_B2F);
  unsigned int*   wpf = (unsigned int*)(ws + WS_WPF);
  unsigned short* b3f = (unsigned short*)(ws + WS_B3F);

  bool mfma_ok = ws_size >= WS_TOTAL_MFMA;
  bool dot2_ok = ws_size >= WS_TOTAL_DOT2;
  int prep_grid = mfma_ok ? 2533 : (dot2_ok ? 181 : 144);
  prep_w_kernel<<<prep_grid, 256, 0, stream>>>(w1, w2, dw_w, b1f, b2f, wpf, b3f);
  if (mfma_ok)
    conv_mfma_kernel<<<3072, 256, 0, stream>>>(x, dw_b, b3f, yc);
  else if (dot2_ok)
    conv_dw_f16_kernel<<<3072, 256, 0, stream>>>(x, dw_b, wpf, yc);
  else
    conv_dw_f32_kernel<<<3072, 256, 0, stream>>>(x, dw_w, dw_b, yc);
  mlp_kernel<<<1024, 256, 0, stream>>>(yc, b1f, b2f, b1, b2, gamma, ln_w, ln_b, mask, out);
}

// Round 8
// 226.980 us; speedup vs baseline: 1.2439x; 1.0522x over previous
//
#include <hip/hip_runtime.h>
#include <hip/hip_bf16.h>

typedef __attribute__((ext_vector_type(2))) float f2v;
typedef __attribute__((ext_vector_type(4))) float f4v;
typedef __attribute__((ext_vector_type(8))) short bf8v;
typedef __attribute__((ext_vector_type(8))) _Float16 h8v;

// ---- problem constants ----
#define NPOS 32768            // 32*32*32
#define CCH  192
#define HID  768

// ---- workspace layout (bytes) ----
#define WS_Y    ((size_t)0)           // 25,165,824  conv out bf16, cell layout
#define WS_B1F  ((size_t)25165824)    // 294,912  w1 bf16 B-frag swizzled
#define WS_B2F  ((size_t)25460736)    // 294,912  w2 bf16 B-frag swizzled
#define WS_WPF  ((size_t)25755648)    // 301,056  dot2 pairs (tier2) / cell list (tier1)
#define WS_B3F  ((size_t)26056704)    // 9,633,792  conv Toeplitz B-frags f16 (192*49 x 1KB)
#define WS_TOTAL_MFMA ((size_t)35690496)
#define WS_TOTAL_DOT2 ((size_t)26056704)

__device__ inline unsigned short f2bf(float f){
  unsigned int u = __float_as_uint(f);
  u += 0x7FFFu + ((u >> 16) & 1u);      // RNE
  return (unsigned short)(u >> 16);
}
__device__ inline float bf2f(unsigned short s){
  return __uint_as_float(((unsigned int)s) << 16);
}
__device__ inline float gelu_f(float x){
  float u = 0.7978845608028654f * x * fmaf(0.044715f, x*x, 1.0f);
  float e = __expf(2.0f*u);
  float th = __fdividef(e - 1.0f, e + 1.0f);
  return 0.5f*x*(1.0f + th);
}

#define DOT2(A, X, W) \
  asm("v_dot2_f32_f16 %0, %1, %2, %0" : "+v"(A) : "v"(X), "s"(W))

// ---------------------------------------------------------------------------
// Kernel 0: mask compaction (1 block). Builds ordered list: active cell ids
// [0..na), then inactive [na..1024); list[1024] = na. Order-preserving so
// consecutive bids (-> round-robin CUs) get evenly spread active cells.
// ---------------------------------------------------------------------------
__global__ __launch_bounds__(256) void compact_kernel(
    const int* __restrict__ mask, int* __restrict__ list)
{
  __shared__ unsigned short cnt[256];
  __shared__ int pref[257];
  int t = threadIdx.x;
  int m[4], c0 = 0;
  #pragma unroll
  for (int i = 0; i < 4; ++i) { m[i] = mask[t*4 + i]; c0 += (m[i] != 0); }
  cnt[t] = (unsigned short)c0;
  __syncthreads();
  if (t == 0) {
    int s = 0;
    for (int i = 0; i < 256; ++i) { pref[i] = s; s += cnt[i]; }
    pref[256] = s;
  }
  __syncthreads();
  int na = pref[256];
  int pa = pref[t];
  int pi = na + (t*4 - pref[t]);
  #pragma unroll
  for (int i = 0; i < 4; ++i) {
    if (m[i]) list[pa++] = t*4 + i;
    else      list[pi++] = t*4 + i;
  }
  if (t == 0) list[1024] = na;
}

// ---------------------------------------------------------------------------
// Kernel 1 (main): depthwise 7x7x7 conv + bias as implicit GEMM on MFMA (f16).
// (Geometry verified r7.) This round: B-frags of a kz loaded as a GROUP of 7
// before the Af ds_reads -- one L2 latency window per kz instead of seven
// 1-deep prefetch stalls.
// ---------------------------------------------------------------------------
#define ZSTR 712
__global__ __launch_bounds__(256) void conv_mfma_kernel(
    const float* __restrict__ x, const float* __restrict__ dw_b,
    const unsigned short* __restrict__ b3f, unsigned short* __restrict__ yc)
{
  __shared__ unsigned short tile[22*ZSTR];    // 31,328 B

  int bid = blockIdx.x;                // 3072 = 192c * 16(r)
  int c = bid % 192;
  int r = bid / 192;                   // 0..15
  int xq = r & 1, yq = (r >> 1) & 1, zh = (r >> 2) & 1, b = r >> 3;
  int tx0 = xq*16, ty0 = yq*16, zb = zh*16;

  int tid = threadIdx.x;
  const float* xsrc = x + ((size_t)(b*CCH + c))*NPOS;

  // ---- stage input: 22z x 22y x 24 real cols (f32->f16), cols 24..31 zero
  #pragma unroll
  for (int it = 0; it < 8; ++it) {
    int idx = tid + 256*it;            // 0..1935 (22*22*4 chunks of 8 halves)
    if (idx < 1936) {
      int ci = idx & 3;
      int row = idx >> 2;
      int lz = row / 22, ly = row - lz*22;
      int gz = zb - 3 + lz, gy = ty0 - 3 + ly;
      f4v v0 = {0.f,0.f,0.f,0.f}, v1 = {0.f,0.f,0.f,0.f};
      if (((unsigned)gz < 32u) & ((unsigned)gy < 32u) & (ci < 3)) {
        int gx0 = tx0 - 4 + 8*ci;
        const float* src = xsrc + (size_t)gz*1024 + gy*32;
        if ((unsigned)gx0 <= 28u)     v0 = *(const f4v*)(src + gx0);
        if ((unsigned)(gx0+4) <= 28u) v1 = *(const f4v*)(src + gx0 + 4);
      }
      h8v pk;
      pk[0] = (_Float16)v0[0]; pk[1] = (_Float16)v0[1];
      pk[2] = (_Float16)v0[2]; pk[3] = (_Float16)v0[3];
      pk[4] = (_Float16)v1[0]; pk[5] = (_Float16)v1[1];
      pk[6] = (_Float16)v1[2]; pk[7] = (_Float16)v1[3];
      *(h8v*)(tile + lz*ZSTR + ly*32 + ci*8) = pk;
    }
  }
  __syncthreads();

  int wv = tid >> 6, lane = tid & 63;
  int q = lane >> 4, zm = lane & 15;   // A-frag: m=zm (z), k-group q

  const unsigned short* abase = tile + (size_t)zm*ZSTR + q*8;
  const unsigned short* bbase = b3f + ((size_t)c*49)*512 + (size_t)lane*8;

  f4v acc[4];
  #pragma unroll
  for (int t = 0; t < 4; ++t) acc[t] = (f4v){0.f,0.f,0.f,0.f};

  #pragma unroll 1
  for (int kz = 0; kz < 7; ++kz) {
    h8v Bt[7];                         // all 7 taps of this kz: loads in flight
    #pragma unroll
    for (int ky = 0; ky < 7; ++ky)
      Bt[ky] = *(const h8v*)(bbase + (size_t)(kz*7 + ky)*512);
    h8v Af[10];                        // rows ly = 4w+0 .. 4w+9, reused over ky
    #pragma unroll
    for (int rr = 0; rr < 10; ++rr)
      Af[rr] = *(const h8v*)(abase + kz*ZSTR + (4*wv + rr)*32);
    #pragma unroll
    for (int ky = 0; ky < 7; ++ky) {
      acc[0] = __builtin_amdgcn_mfma_f32_16x16x32_f16(Af[ky+0], Bt[ky], acc[0], 0, 0, 0);
      acc[1] = __builtin_amdgcn_mfma_f32_16x16x32_f16(Af[ky+1], Bt[ky], acc[1], 0, 0, 0);
      acc[2] = __builtin_amdgcn_mfma_f32_16x16x32_f16(Af[ky+2], Bt[ky], acc[2], 0, 0, 0);
      acc[3] = __builtin_amdgcn_mfma_f32_16x16x32_f16(Af[ky+3], Bt[ky], acc[3], 0, 0, 0);
    }
  }

  // ---- store: C col=lane&15 -> ox, row=q*4+r -> oz; tok = dz*16 + dy*4 + dx
  float bias = dw_b[c];
  int cz = zh*4 + q;
  int cx = (tx0 >> 2) + (zm >> 2);
  int xr = zm & 3;
  int cy = (ty0 >> 2) + wv;
  int cell = cz*64 + cy*8 + cx;
  unsigned short* yb0 = yc + (((size_t)(b*512 + cell))*192 + c)*64 + xr;
  #pragma unroll
  for (int t = 0; t < 4; ++t) {
    unsigned short* yb = yb0 + t*4;
    yb[0]  = f2bf(acc[t][0] + bias);
    yb[16] = f2bf(acc[t][1] + bias);
    yb[32] = f2bf(acc[t][2] + bias);
    yb[48] = f2bf(acc[t][3] + bias);
  }
}

// ---------------------------------------------------------------------------
// Kernel 1 (tier-2 fallback): dot2 f16 path.
// ---------------------------------------------------------------------------
__global__ __launch_bounds__(256, 6) void conv_dw_f16_kernel(
    const float* __restrict__ x, const float* __restrict__ dw_b,
    const unsigned int* __restrict__ wpf, unsigned short* __restrict__ yc)
{
  __shared__ unsigned short ring[22*528];

  int bid = blockIdx.x;
  int c = bid % 192;
  int r = bid / 192;
  int xq = r & 1, yq = (r >> 1) & 1, zh = (r >> 2) & 1, b = r >> 3;
  int tx0 = xq*16, ty0 = yq*16, zb = zh*16;

  int tid = threadIdx.x;
  const float* xsrc = x + ((size_t)(b*CCH + c))*NPOS;

  for (int idx = tid; idx < 2904; idx += 256) {
    int sl = idx / 132;
    int rem = idx - sl*132;
    int rr = rem / 6, ci = rem - rr*6;
    int zi = zb - 3 + sl, gy = ty0 - 3 + rr, gx = tx0 - 4 + 4*ci;
    f4v v = {0.f, 0.f, 0.f, 0.f};
    if ((unsigned)zi < 32u && (unsigned)gy < 32u && (unsigned)gx <= 28u)
      v = *(const f4v*)(xsrc + (size_t)zi*1024 + gy*32 + gx);
    union { _Float16 h[4]; uint2 u2; } pk;
    pk.h[0] = (_Float16)v[0]; pk.h[1] = (_Float16)v[1];
    pk.h[2] = (_Float16)v[2]; pk.h[3] = (_Float16)v[3];
    *(uint2*)(ring + sl*528 + rr*24 + ci*4) = pk.u2;
  }
  __syncthreads();

  int p = tid & 15, zl = tid >> 4;
  int px = p & 3, py = p >> 2;
  int y0 = py*4, px4 = px*4;
  const unsigned short* base = ring + zl*528 + y0*24 + px4;
  const unsigned int* wb = wpf + (size_t)c*392;

  float acc[4][4];
  #pragma unroll
  for (int i = 0; i < 4; ++i)
    #pragma unroll
    for (int j = 0; j < 4; ++j) acc[i][j] = 0.f;

  #pragma unroll 1
  for (int s = 0; s < 7; ++s) {
    const unsigned short* sb = base + s*528;
    const unsigned int* wrow = wb + s*56;
    #pragma unroll
    for (int rr = 0; rr < 10; ++rr) {
      const unsigned short* rb = sb + rr*24;
      uint2 q0 = *(const uint2*)(rb);
      uint2 q1 = *(const uint2*)(rb + 4);
      uint2 q2 = *(const uint2*)(rb + 8);
      unsigned int D[6] = {q0.x, q0.y, q1.x, q1.y, q2.x, q2.y};
      #pragma unroll
      for (int dy = 0; dy < 4; ++dy) {
        int ky = rr - dy;
        if (ky < 0 || ky > 6) continue;
        const unsigned int* wk = wrow + ky*8;
        #pragma unroll
        for (int t = 0; t < 4; ++t) {
          DOT2(acc[dy][0], D[t],   wk[t]);
          DOT2(acc[dy][1], D[t+1], wk[4+t]);
          DOT2(acc[dy][2], D[t+1], wk[t]);
          DOT2(acc[dy][3], D[t+2], wk[4+t]);
        }
      }
    }
  }

  float bias = dw_b[c];
  int z = zb + zl;
  int cz = z >> 2, cx = (tx0 >> 2) + px, cy = (ty0 >> 2) + py;
  int cell = cz*64 + cy*8 + cx;
  unsigned short* ybase = yc + (((size_t)(b*512 + cell))*192 + c)*64;
  int tokz = (z & 3)*16;
  #pragma unroll
  for (int dy = 0; dy < 4; ++dy) {
    ushort4 o;
    o.x = f2bf(acc[dy][0] + bias);
    o.y = f2bf(acc[dy][1] + bias);
    o.z = f2bf(acc[dy][2] + bias);
    o.w = f2bf(acc[dy][3] + bias);
    *(ushort4*)(ybase + tokz + dy*4) = o;
  }
}

// ---------------------------------------------------------------------------
// Kernel 1 (tier-3 fallback): fp32 C path.
// ---------------------------------------------------------------------------
__global__ __launch_bounds__(256) void conv_dw_f32_kernel(
    const float* __restrict__ x, const float* __restrict__ dw_w,
    const float* __restrict__ dw_b, unsigned short* __restrict__ yc)
{
  __shared__ float ring[22*528];

  int bid = blockIdx.x;
  int c = bid % 192;
  int r = bid / 192;
  int xq = r & 1, yq = (r >> 1) & 1, zh = (r >> 2) & 1, b = r >> 3;
  int tx0 = xq*16, ty0 = yq*16, zb = zh*16;

  int tid = threadIdx.x;
  const float* xsrc = x + ((size_t)(b*CCH + c))*NPOS;

  for (int idx = tid; idx < 2904; idx += 256) {
    int sl = idx / 132;
    int rem = idx - sl*132;
    int rr = rem / 6, ci = rem - rr*6;
    int zi = zb - 3 + sl, gy = ty0 - 3 + rr, gx = tx0 - 4 + 4*ci;
    f4v v = {0.f, 0.f, 0.f, 0.f};
    if ((unsigned)zi < 32u && (unsigned)gy < 32u && (unsigned)gx <= 28u)
      v = *(const f4v*)(xsrc + (size_t)zi*1024 + gy*32 + gx);
    *(f4v*)(ring + sl*528 + rr*24 + ci*4) = v;
  }
  __syncthreads();

  int p = tid & 15, zl = tid >> 4;
  int px = p & 3, py = p >> 2;
  int y0 = py*4, px4 = px*4;
  const float* base = ring + zl*528 + y0*24 + px4;
  const float* wbase = dw_w + (size_t)c*343;

  f2v acc[8];
  #pragma unroll
  for (int i = 0; i < 8; ++i) acc[i] = (f2v){0.f, 0.f};

  #pragma unroll 1
  for (int s = 0; s < 7; ++s) {
    const float* sb = base + s*528;
    f4v n0 = *(const f4v*)(sb);
    f4v n1 = *(const f4v*)(sb + 4);
    f4v n2 = *(const f4v*)(sb + 8);
    #pragma unroll
    for (int rr = 0; rr < 10; ++rr) {
      f4v r0 = n0, r1 = n1, r2 = n2;
      if (rr < 9) {
        n0 = *(const f4v*)(sb + (rr+1)*24);
        n1 = *(const f4v*)(sb + (rr+1)*24 + 4);
        n2 = *(const f4v*)(sb + (rr+1)*24 + 8);
      }
      f2v pr[10];
      pr[1] = (f2v){r0[1], r0[2]};
      pr[2] = (f2v){r0[2], r0[3]};
      pr[3] = (f2v){r0[3], r1[0]};
      pr[4] = (f2v){r1[0], r1[1]};
      pr[5] = (f2v){r1[1], r1[2]};
      pr[6] = (f2v){r1[2], r1[3]};
      pr[7] = (f2v){r1[3], r2[0]};
      pr[8] = (f2v){r2[0], r2[1]};
      pr[9] = (f2v){r2[1], r2[2]};
      #pragma unroll
      for (int dy = 0; dy < 4; ++dy) {
        int ky = rr - dy;
        if (ky < 0 || ky > 6) continue;
        #pragma unroll
        for (int kx = 0; kx < 7; ++kx) {
          float w = wbase[s*49 + ky*7 + kx];
          f2v wv = (f2v){w, w};
          acc[dy*2+0] = __builtin_elementwise_fma(wv, pr[kx+1], acc[dy*2+0]);
          acc[dy*2+1] = __builtin_elementwise_fma(wv, pr[kx+3], acc[dy*2+1]);
        }
      }
    }
  }

  float bias = dw_b[c];
  int z = zb + zl;
  int cz = z >> 2, cx = (tx0 >> 2) + px, cy = (ty0 >> 2) + py;
  int cell = cz*64 + cy*8 + cx;
  unsigned short* ybase = yc + (((size_t)(b*512 + cell))*192 + c)*64;
  int tokz = (z & 3)*16;
  #pragma unroll
  for (int dy = 0; dy < 4; ++dy) {
    ushort4 o;
    o.x = f2bf(acc[dy*2+0][0] + bias);
    o.y = f2bf(acc[dy*2+0][1] + bias);
    o.z = f2bf(acc[dy*2+1][0] + bias);
    o.w = f2bf(acc[dy*2+1][1] + bias);
    *(ushort4*)(ybase + tokz + dy*4) = o;
  }
}

// ---------------------------------------------------------------------------
// Kernel 2: weight prep (unchanged).
// ---------------------------------------------------------------------------
__global__ __launch_bounds__(256) void prep_w_kernel(
    const float* __restrict__ w1, const float* __restrict__ w2,
    const float* __restrict__ dw_w,
    unsigned short* __restrict__ b1f, unsigned short* __restrict__ b2f,
    unsigned int* __restrict__ wpf, unsigned short* __restrict__ b3f)
{
  int gid = blockIdx.x*256 + threadIdx.x;
  if (gid < 18432) {
    int fi = gid;                         // w1 (C=192 x HID=768)
    int lane = fi & 63, fr = fi >> 6;
    int nt = fr / 6, ks = fr - nt*6;
    int n  = nt*16 + (lane & 15);
    int kb = ks*32 + (lane >> 4)*8;
    #pragma unroll
    for (int j = 0; j < 8; ++j) b1f[fi*8 + j] = f2bf(w1[(kb+j)*HID + n]);
  } else if (gid < 36864) {
    int fi = gid - 18432;                 // w2 (HID=768 x C=192)
    int lane = fi & 63, fr = fi >> 6;
    int nt = fr / 24, ks = fr - nt*24;
    int n  = nt*16 + (lane & 15);
    int kb = ks*32 + (lane >> 4)*8;
    #pragma unroll
    for (int j = 0; j < 8; ++j) b2f[fi*8 + j] = f2bf(w2[(kb+j)*CCH + n]);
  } else if (gid < 46272) {
    int ci = gid - 36864;                 // 192*49 dot2 rows (tier-2)
    int cch = ci / 49, t7 = ci - cch*49;
    const float* wr = dw_w + cch*343 + t7*7;
    float w[8];
    #pragma unroll
    for (int j = 0; j < 7; ++j) w[j] = wr[j];
    w[7] = 0.f;
    union { _Float16 h[2]; unsigned int u; } pk;
    #pragma unroll
    for (int t = 0; t < 4; ++t) {
      pk.h[0] = (t == 0) ? (_Float16)0.f : (_Float16)w[2*t-1];
      pk.h[1] = (_Float16)w[2*t];
      wpf[ci*8 + t] = pk.u;
    }
    #pragma unroll
    for (int t = 0; t < 4; ++t) {
      pk.h[0] = (_Float16)w[2*t];
      pk.h[1] = (_Float16)w[2*t+1];
      wpf[ci*8 + 4 + t] = pk.u;
    }
  } else if (gid < 648384) {
    int fi = gid - 46272;                 // 9408 frags x 64 lanes
    int lane = fi & 63, frag = fi >> 6;
    int cch = frag / 49, tap = frag - cch*49;
    const float* wr = dw_w + cch*343 + tap*7;
    int q = lane >> 4, n = lane & 15;
    h8v pk;
    #pragma unroll
    for (int j = 0; j < 8; ++j) {
      int t = q*8 + j - n - 1;
      pk[j] = (t >= 0 && t <= 6) ? (_Float16)wr[t] : (_Float16)0.f;
    }
    *(h8v*)(b3f + (size_t)fi*8) = pk;
  }
}

// ---------------------------------------------------------------------------
// Kernel 3: fused LN + MLP. COMPACT=1: block bid processes cell list[bid];
// bid < list[1024] -> active MLP, else zero-fill for that (inactive) cell.
// Ordered compaction spreads active cells evenly over CUs (kills the
// random-mask tail that held occupancy at 11.6%). COMPACT=0: old mask path.
// ---------------------------------------------------------------------------
template<int COMPACT>
__global__ __launch_bounds__(256) void mlp_kernel(
    const unsigned short* __restrict__ yc, const unsigned short* __restrict__ b1f,
    const unsigned short* __restrict__ b2f, const float* __restrict__ b1,
    const float* __restrict__ b2, const float* __restrict__ gamma,
    const float* __restrict__ ln_w, const float* __restrict__ ln_b,
    const int* __restrict__ mask, const int* __restrict__ list,
    float* __restrict__ out)
{
  int bid = blockIdx.x;
  int cid, active;
  if constexpr (COMPACT) {
    int na = list[1024];
    cid = list[bid];
    active = bid < na;
  } else {
    cid = bid;
    active = (mask[bid] != 0);
  }
  int b = cid >> 9, cell = cid & 511;
  int cz = cell >> 6, cy = (cell >> 3) & 7, cx = cell & 7;
  int z0 = cz*4, y0 = cy*4, x0 = cx*4;
  int tid = threadIdx.x, wave = tid >> 6, lane = tid & 63;
  int lq = lane >> 4, ln15 = lane & 15;

  if (!active) {
    f4v z4 = {0.f, 0.f, 0.f, 0.f};
    #pragma unroll
    for (int pp = 0; pp < 12; ++pp) {
      int i4 = tid + 256*pp;
      int c = i4 >> 4, rem = i4 & 15;
      int dz = rem >> 2, dy = rem & 3;
      *(f4v*)(out + ((size_t)(b*CCH + c))*NPOS
                  + (size_t)(z0+dz)*1024 + (y0+dy)*32 + x0) = z4;
    }
    return;
  }

  __shared__ __align__(16) char uni[26112];
  unsigned short* ymat = (unsigned short*)uni;
  unsigned short* hbuf = (unsigned short*)uni;
  __shared__ unsigned short aFrag[12288];
  __shared__ float sred[2][4][64];
  __shared__ float murs[2][64];

  const unsigned short* ysrc = yc + (size_t)cid*12288;

  #pragma unroll
  for (int k = 0; k < 12; ++k) {
    int idx = tid + 256*k;
    int c = idx >> 4, t4 = idx & 15;
    *(ushort4*)(ymat + c*68 + t4*4) = *(const ushort4*)(ysrc + c*64 + t4*4);
  }
  __syncthreads();

  {
    int tok = tid & 63, part = tid >> 6;
    float S = 0.f, Q = 0.f;
    #pragma unroll
    for (int j = 0; j < 48; ++j) {
      float v = bf2f(ymat[(part*48 + j)*68 + tok]);
      S += v; Q = fmaf(v, v, Q);
    }
    sred[0][part][tok] = S; sred[1][part][tok] = Q;
  }
  __syncthreads();
  if (tid < 64) {
    float S = sred[0][0][tid] + sred[0][1][tid] + sred[0][2][tid] + sred[0][3][tid];
    float Q = sred[1][0][tid] + sred[1][1][tid] + sred[1][2][tid] + sred[1][3][tid];
    float m = S*(1.f/192.f);
    float var = Q*(1.f/192.f) - m*m;
    murs[0][tid] = m;
    murs[1][tid] = rsqrtf(var + 1e-6f);
  }
  __syncthreads();

  #pragma unroll
  for (int k = 0; k < 6; ++k) {
    int fi = tid + 256*k;
    int lane2 = fi & 63, rest = fi >> 6;
    int mt = rest / 6, ks = rest - mt*6;
    int tok = mt*16 + (lane2 & 15);
    int cc0 = ks*32 + (lane2 >> 4)*8;
    float m = murs[0][tok], rs = murs[1][tok];
    f4v lw0 = *(const f4v*)(ln_w + cc0), lw1 = *(const f4v*)(ln_w + cc0 + 4);
    f4v lb0 = *(const f4v*)(ln_b + cc0), lb1 = *(const f4v*)(ln_b + cc0 + 4);
    union { bf8v v; unsigned short u[8]; } pk;
    #pragma unroll
    for (int j = 0; j < 4; ++j) {
      float v0 = (bf2f(ymat[(cc0+j)*68 + tok])   - m)*rs*lw0[j] + lb0[j];
      float v1 = (bf2f(ymat[(cc0+4+j)*68 + tok]) - m)*rs*lw1[j] + lb1[j];
      pk.u[j] = f2bf(v0); pk.u[4+j] = f2bf(v1);
    }
    *(bf8v*)(aFrag + fi*8) = pk.v;
  }
  __syncthreads();

  f4v acc2[4][3];
  #pragma unroll
  for (int mt = 0; mt < 4; ++mt)
    #pragma unroll
    for (int nt = 0; nt < 3; ++nt)
      acc2[mt][nt] = (f4v){0.f, 0.f, 0.f, 0.f};

  const unsigned short* p1base = b1f + wave*2*3072 + lane*8;
  const unsigned short* p2base = b2f + wave*3*12288 + lane*8;

  bf8v B1r[12];
  #pragma unroll
  for (int i = 0; i < 12; ++i) {
    int jj = i / 6, ks = i - jj*6;
    B1r[i] = *(const bf8v*)(p1base + jj*3072 + ks*512);
  }

  #pragma unroll 1
  for (int ch = 0; ch < 6; ++ch) {
    bf8v B2r[12];
    const unsigned short* p2 = p2base + ch*2048;
    #pragma unroll
    for (int ks2 = 0; ks2 < 4; ++ks2)
      #pragma unroll
      for (int nt = 0; nt < 3; ++nt)
        B2r[ks2*3 + nt] = *(const bf8v*)(p2 + nt*12288 + ks2*512);

    f4v a1[2][4];
    #pragma unroll
    for (int jj = 0; jj < 2; ++jj)
      #pragma unroll
      for (int mt = 0; mt < 4; ++mt) a1[jj][mt] = (f4v){0.f,0.f,0.f,0.f};
    #pragma unroll
    for (int ks = 0; ks < 6; ++ks) {
      bf8v Af[4];
      #pragma unroll
      for (int mt = 0; mt < 4; ++mt)
        Af[mt] = *(const bf8v*)(aFrag + ((mt*6 + ks)*64 + lane)*8);
      #pragma unroll
      for (int jj = 0; jj < 2; ++jj)
        #pragma unroll
        for (int mt = 0; mt < 4; ++mt)
          a1[jj][mt] = __builtin_amdgcn_mfma_f32_16x16x32_bf16(Af[mt], B1r[jj*6+ks], a1[jj][mt], 0, 0, 0);
    }

    if (ch < 5) {
      const unsigned short* p1 = p1base + (ch+1)*24576;
      #pragma unroll
      for (int i = 0; i < 12; ++i) {
        int jj = i / 6, ks = i - jj*6;
        B1r[i] = *(const bf8v*)(p1 + jj*3072 + ks*512);
      }
    }

    #pragma unroll
    for (int jj = 0; jj < 2; ++jj) {
      float b1v = b1[(ch*8 + wave*2 + jj)*16 + ln15];
      int lane_hi = jj*2 + (ln15 >> 3);
      #pragma unroll
      for (int mt = 0; mt < 4; ++mt)
        #pragma unroll
        for (int rr = 0; rr < 4; ++rr) {
          float g = gelu_f(a1[jj][mt][rr] + b1v);
          int elem = ((mt*4 + wave)*64 + lane_hi*16 + (lq*4 + rr))*8 + (lane & 7);
          hbuf[elem] = f2bf(g);
        }
    }
    __syncthreads();
    #pragma unroll
    for (int ks2 = 0; ks2 < 4; ++ks2) {
      bf8v A2[4];
      #pragma unroll
      for (int mt = 0; mt < 4; ++mt)
        A2[mt] = *(const bf8v*)(hbuf + ((mt*4 + ks2)*64 + lane)*8);
      #pragma unroll
      for (int nt = 0; nt < 3; ++nt)
        #pragma unroll
        for (int mt = 0; mt < 4; ++mt)
          acc2[mt][nt] = __builtin_amdgcn_mfma_f32_16x16x32_bf16(A2[mt], B2r[ks2*3+nt], acc2[mt][nt], 0, 0, 0);
    }
    __syncthreads();
  }

  #pragma unroll
  for (int nt = 0; nt < 3; ++nt) {
    int c = (wave*3 + nt)*16 + ln15;
    float gm = gamma[c], bb = b2[c];
    size_t cbase = ((size_t)(b*CCH + c))*NPOS + (size_t)(y0 + lq)*32 + x0;
    #pragma unroll
    for (int mt = 0; mt < 4; ++mt) {
      f4v o;
      o[0] = gm*(acc2[mt][nt][0] + bb);
      o[1] = gm*(acc2[mt][nt][1] + bb);
      o[2] = gm*(acc2[mt][nt][2] + bb);
      o[3] = gm*(acc2[mt][nt][3] + bb);
      *(f4v*)(out + cbase + (size_t)(z0 + mt)*1024) = o;
    }
  }
}

// ---------------------------------------------------------------------------
extern "C" void kernel_launch(void* const* d_in, const int* in_sizes, int n_in,
                              void* d_out, int out_size, void* d_ws, size_t ws_size,
                              hipStream_t stream) {
  const float* x     = (const float*)d_in[0];
  const int*   mask  = (const int*)  d_in[1];
  const float* dw_w  = (const float*)d_in[2];
  const float* dw_b  = (const float*)d_in[3];
  const float* ln_w  = (const float*)d_in[4];
  const float* ln_b  = (const float*)d_in[5];
  const float* w1    = (const float*)d_in[6];
  const float* b1    = (const float*)d_in[7];
  const float* w2    = (const float*)d_in[8];
  const float* b2    = (const float*)d_in[9];
  const float* gamma = (const float*)d_in[10];
  float* out = (float*)d_out;
  char* ws = (char*)d_ws;

  unsigned short* yc  = (unsigned short*)(ws + WS_Y);
  unsigned short* b1f = (unsigned short*)(ws + WS_B1F);
  unsigned short* b2f = (unsigned short*)(ws + WS_B2F);
  unsigned int*   wpf = (unsigned int*)(ws + WS_WPF);
  unsigned short* b3f = (unsigned short*)(ws + WS_B3F);
  int*            lst = (int*)(ws + WS_WPF);   // mfma tier: wpf slot unused

  bool mfma_ok = ws_size >= WS_TOTAL_MFMA;
  bool dot2_ok = ws_size >= WS_TOTAL_DOT2;
  int prep_grid = mfma_ok ? 2533 : (dot2_ok ? 181 : 144);
  prep_w_kernel<<<prep_grid, 256, 0, stream>>>(w1, w2, dw_w, b1f, b2f, wpf, b3f);
  if (mfma_ok) {
    compact_kernel<<<1, 256, 0, stream>>>(mask, lst);
    conv_mfma_kernel<<<3072, 256, 0, stream>>>(x, dw_b, b3f, yc);
    mlp_kernel<1><<<1024, 256, 0, stream>>>(yc, b1f, b2f, b1, b2, gamma, ln_w, ln_b, mask, lst, out);
  } else if (dot2_ok) {
    conv_dw_f16_kernel<<<3072, 256, 0, stream>>>(x, dw_b, wpf, yc);
    mlp_kernel<0><<<1024, 256, 0, stream>>>(yc, b1f, b2f, b1, b2, gamma, ln_w, ln_b, mask, nullptr, out);
  } else {
    conv_dw_f32_kernel<<<3072, 256, 0, stream>>>(x, dw_w, dw_b, yc);
    mlp_kernel<0><<<1024, 256, 0, stream>>>(yc, b1f, b2f, b1, b2, gamma, ln_w, ln_b, mask, nullptr, out);
  }
}